// Round 6
// baseline (417.703 us; speedup 1.0000x reference)
//
#include <hip/hip_runtime.h>
#include <hip/hip_bf16.h>
#include <cstdint>

#define T_SEQ 2048
#define DIM   1024
#define NHEAD 16
#define NKVH  8
#define HDIM  64
#define QKVN  3584   // 2048 (q) + 1024 (k) + 512 (v)

static constexpr float LAMBDA_INIT_F = 0.3555090675909693f;
static constexpr float ONE_MINUS_LI  = 0.6444909324090307f;

typedef __bf16 bf16x8 __attribute__((ext_vector_type(8)));
typedef float  f32x4  __attribute__((ext_vector_type(4)));

static __device__ __forceinline__ ushort f2bf(float f) {
  union { float f; uint32_t u; } x; x.f = f;
  uint32_t u = x.u;
  uint32_t r = (u + 0x7fffu + ((u >> 16) & 1u)) >> 16;
  return (ushort)r;
}
static __device__ __forceinline__ float bf2f(ushort u) {
  union { uint32_t u; float f; } x; x.u = ((uint32_t)u) << 16; return x.f;
}
static __device__ __forceinline__ f32x4 zero4() {
  f32x4 z = {0.f, 0.f, 0.f, 0.f}; return z;
}
// Load one 8-element A/B fragment for mfma_f32_16x16x32_bf16.
// Per-lane k layout: halves at k = 4*(lane>>4) and k = 16 + 4*(lane>>4).
static __device__ __forceinline__ bf16x8 ldfrag(const ushort* p) {
  union { bf16x8 v; uint2 u[2]; } r;
  r.u[0] = *(const uint2*)(p);
  r.u[1] = *(const uint2*)(p + 16);
  return r.v;
}
// async global->LDS, 16B per lane; lds dest = base + lane*16 (wave-uniform base)
static __device__ __forceinline__ void gll16(const ushort* g, ushort* l) {
  __builtin_amdgcn_global_load_lds(
      (const __attribute__((address_space(1))) uint32_t*)g,
      (__attribute__((address_space(3))) uint32_t*)l, 16, 0, 0);
}

// ---------------- fused fp32->bf16 conversion (vectorized x4) ----------------
__global__ void cvt_all(const float* __restrict__ x,  const float* __restrict__ wq,
                        const float* __restrict__ wk, const float* __restrict__ wv,
                        const float* __restrict__ wo,
                        ushort* __restrict__ xb, ushort* __restrict__ Wb,
                        ushort* __restrict__ Wob) {
  int g = (blockIdx.x * 256 + threadIdx.x) * 4;   // < 6815744
  float4 v; ushort* dst;
  if (g < 2097152) {
    v = *(const float4*)(x + g); dst = xb + g;
  } else if (g < 5767168) {
    int j = g - 2097152;
    const float* src = (j < 2097152) ? (wq + j)
                     : (j < 3145728) ? (wk + (j - 2097152))
                                     : (wv + (j - 3145728));
    v = *(const float4*)src; dst = Wb + j;
  } else {
    int j = g - 5767168;
    v = *(const float4*)(wo + j); dst = Wob + j;
  }
  ushort4 o4;
  o4.x = f2bf(v.x); o4.y = f2bf(v.y); o4.z = f2bf(v.z); o4.w = f2bf(v.w);
  *(ushort4*)dst = o4;
}

__global__ void lam_kernel(const float* __restrict__ lq1, const float* __restrict__ lk1,
                           const float* __restrict__ lq2, const float* __restrict__ lk2,
                           float* __restrict__ lam) {
  int lane = threadIdx.x;  // 64 threads
  float p1 = lq1[lane] * lk1[lane];
  float p2 = lq2[lane] * lk2[lane];
  #pragma unroll
  for (int off = 32; off >= 1; off >>= 1) {
    p1 += __shfl_down(p1, off);
    p2 += __shfl_down(p2, off);
  }
  if (lane == 0) *lam = expf(p1) - expf(p2) + LAMBDA_INIT_F;
}

// ---------------- GEMM: C[M][N] = A[M][K] @ W[N][K]^T, m97 structure ----------------
template<int BF16OUT>
__global__ __launch_bounds__(256) void gemm_bt(const ushort* __restrict__ A,
                                               const ushort* __restrict__ W,
                                               void* __restrict__ Cout,
                                               int M, int N, int K) {
  __shared__ ushort As[128 * 32];
  __shared__ ushort Ws[128 * 32];
  const int tid  = threadIdx.x;
  const int lane = tid & 63;
  const int w    = tid >> 6;
  const int wr   = w >> 1, wc = w & 1;
  const int bm   = blockIdx.y * 128, bn = blockIdx.x * 128;
  const int fr   = lane & 15;
  const int fg   = (lane >> 4) * 4;

  f32x4 acc[4][4];
  #pragma unroll
  for (int m = 0; m < 4; ++m)
    #pragma unroll
    for (int n = 0; n < 4; ++n) acc[m][n] = zero4();

  const int col  = (lane & 3) * 8;
  const int row0 = w * 16 + (lane >> 2);
  const int row1 = row0 + 64;
  const ushort* ga0 = A + (size_t)(bm + row0) * K + col;
  const ushort* ga1 = A + (size_t)(bm + row1) * K + col;
  const ushort* gw0 = W + (size_t)(bn + row0) * K + col;
  const ushort* gw1 = W + (size_t)(bn + row1) * K + col;
  ushort* la0 = As + (w * 512);
  ushort* la1 = As + (w * 512) + 2048;
  ushort* lw0 = Ws + (w * 512);
  ushort* lw1 = Ws + (w * 512) + 2048;

  for (int k0 = 0; k0 < K; k0 += 32) {
    gll16(ga0 + k0, la0);
    gll16(ga1 + k0, la1);
    gll16(gw0 + k0, lw0);
    gll16(gw1 + k0, lw1);
    __syncthreads();
    bf16x8 af[4], bfr[4];
    #pragma unroll
    for (int m = 0; m < 4; ++m) af[m]  = ldfrag(&As[(wr*64 + m*16 + fr) * 32 + fg]);
    #pragma unroll
    for (int n = 0; n < 4; ++n) bfr[n] = ldfrag(&Ws[(wc*64 + n*16 + fr) * 32 + fg]);
    #pragma unroll
    for (int m = 0; m < 4; ++m)
      #pragma unroll
      for (int n = 0; n < 4; ++n)
        acc[m][n] = __builtin_amdgcn_mfma_f32_16x16x32_bf16(af[m], bfr[n], acc[m][n], 0, 0, 0);
    __syncthreads();
  }

  #pragma unroll
  for (int m = 0; m < 4; ++m)
    #pragma unroll
    for (int n = 0; n < 4; ++n)
      #pragma unroll
      for (int i = 0; i < 4; ++i) {
        int row = bm + wr*64 + m*16 + fg + i;
        int colg = bn + wc*64 + n*16 + fr;
        float v = acc[m][n][i];
        if (BF16OUT) ((ushort*)Cout)[(size_t)row * N + colg] = f2bf(v);
        else         ((float*)Cout)[(size_t)row * N + colg]  = v;
      }
}

// ---------------- fused RoPE Q, RoPE K, pack V (vectorized) ----------------
__global__ void reorg(const ushort* __restrict__ QKV, ushort* __restrict__ Qr,
                      ushort* __restrict__ Kr, ushort* __restrict__ Vt,
                      const float* __restrict__ fc, const float* __restrict__ fs) {
  int idx = blockIdx.x * 256 + threadIdx.x;   // < 917504
  if (idx < 786432) {
    // RoPE, 4 interleaved pairs (8 bf16) per thread
    int nheads, col_off; ushort* dst; float scale; int id;
    if (idx < 524288) { id = idx * 4; nheads = NHEAD; col_off = 0; dst = Qr; scale = 0.125f; }
    else { id = (idx - 524288) * 4; nheads = NKVH; col_off = 2048; dst = Kr; scale = 1.0f; }
    int per_t = nheads * 64;
    int t  = id / per_t;
    int r  = id - t * per_t;
    int hh = r >> 6;
    int c2 = (r >> 5) & 1;
    int j  = r & 31;                      // multiple of 4
    int cl = col_off + hh * 128 + c2 * 64 + 2 * j;
    uint4 raw = *(const uint4*)(QKV + (size_t)t * QKVN + cl);
    const ushort* rp = (const ushort*)&raw;
    float c4[4], s4[4];
    *(float4*)c4 = *(const float4*)(fc + t * 32 + j);
    *(float4*)s4 = *(const float4*)(fs + t * 32 + j);
    ushort outv[8];
    #pragma unroll
    for (int p = 0; p < 4; ++p) {
      float rv = bf2f(rp[2*p]), iv = bf2f(rp[2*p + 1]);
      outv[2*p]     = f2bf((rv * c4[p] - iv * s4[p]) * scale);
      outv[2*p + 1] = f2bf((rv * s4[p] + iv * c4[p]) * scale);
    }
    size_t o = ((size_t)(c2 * nheads + hh) * T_SEQ + t) * HDIM + 2 * j;
    *(uint4*)(dst + o) = *(const uint4*)outv;
  } else {
    // V transpose: 8 t-consecutive elems -> one contiguous store
    int id = (idx - 786432) * 8;           // < 1048576
    int t = id & (T_SEQ - 1);              // multiple of 8
    int rest = id >> 11;                   // kh*64 + d
    ushort outv[8];
    #pragma unroll
    for (int p = 0; p < 8; ++p) outv[p] = QKV[(size_t)(t + p) * QKVN + 3072 + rest];
    *(uint4*)(Vt + (size_t)rest * T_SEQ + t) = *(const uint4*)outv;
  }
}

// ---------------- flash attention: split-K chunks, swapped QK^T, P in-register -----
// Block = (qb, stream st, head h, chunk c). Chunk covers tiles [kt0, kt1) (<=16).
// Emits normalized O (bf16) + (m, l) per q-row; merge_stats combines.
__global__ __launch_bounds__(256) void attn_kernel(const ushort* __restrict__ Qr,
                                                   const ushort* __restrict__ Kr,
                                                   const ushort* __restrict__ Vt,
                                                   ushort* __restrict__ On,
                                                   float* __restrict__ Ml) {
  const int bx = blockIdx.x;            // 0..2047, heaviest qb first
  const int qb = 31 - (bx >> 6);
  const int rem = bx & 63;
  const int st = rem >> 5;
  const int h  = (rem >> 1) & 15;
  const int c  = rem & 1;
  const int kh = h >> 1;
  const int s0 = (qb + 2) >> 1;
  const int kt0 = c ? s0 : 0;
  const int kt1 = c ? (qb + 1) : s0;

  const int tid = threadIdx.x;
  const int lane = tid & 63;
  const int w   = tid >> 6;
  const int fr  = lane & 15;
  const int fg  = (lane >> 4) * 4;

  __shared__ ushort Ks[64][70];
  __shared__ ushort Vs[64][70];      // [d][s], stride 70 = conflict-free

  // Q fragments (pre-scaled by 1/8); B-operand (col = q row)
  bf16x8 qf[2];
  {
    const int row = qb * 64 + w * 16 + fr;
    const ushort* qp = Qr + ((size_t)(st * NHEAD + h) * T_SEQ + row) * HDIM;
    qf[0] = ldfrag(qp + fg);
    qf[1] = ldfrag(qp + 32 + fg);
  }

  float m_ = -__builtin_inff(), l_ = 0.f;
  f32x4 o_[4];
  #pragma unroll
  for (int dn = 0; dn < 4; ++dn) o_[dn] = zero4();

  // K/V prefetch registers
  const int srow = tid >> 2, scol = (tid & 3) * 16;
  uint4 kpre[2], vpre[2];
  const ushort* ksrc0 = Kr + ((size_t)(st * NKVH + kh) * T_SEQ + srow) * HDIM + scol;
  const ushort* vsrc0 = Vt + (size_t)(kh * 64 + srow) * T_SEQ + scol;
  if (kt0 < kt1) {
    const ushort* ks = ksrc0 + (size_t)kt0 * 64 * HDIM;
    const ushort* vs = vsrc0 + (size_t)kt0 * 64;
    kpre[0] = *(const uint4*)ks;
    kpre[1] = *(const uint4*)(ks + 8);
    vpre[0] = *(const uint4*)vs;
    vpre[1] = *(const uint4*)(vs + 8);
  }

  for (int kt = kt0; kt < kt1; ++kt) {
    __syncthreads();                 // prev iteration's LDS reads complete
    *(uint4*)&Ks[srow][scol]     = kpre[0];
    *(uint4*)&Ks[srow][scol + 8] = kpre[1];
    *(uint4*)&Vs[srow][scol]     = vpre[0];
    *(uint4*)&Vs[srow][scol + 8] = vpre[1];
    if (kt + 1 < kt1) {              // issue next tile's loads; hide under compute
      const ushort* ks = ksrc0 + (size_t)(kt + 1) * 64 * HDIM;
      const ushort* vs = vsrc0 + (size_t)(kt + 1) * 64;
      kpre[0] = *(const uint4*)ks;
      kpre[1] = *(const uint4*)(ks + 8);
      vpre[0] = *(const uint4*)vs;
      vpre[1] = *(const uint4*)(vs + 8);
    }
    __syncthreads();                 // staging visible

    // S^T tile: mfma(K rows, Q cols) -> lane holds q=fr, keys n*16+fg+i
    float sv[4][4];
    #pragma unroll
    for (int n = 0; n < 4; ++n) {
      f32x4 acc = zero4();
      #pragma unroll
      for (int ks = 0; ks < 2; ++ks) {
        bf16x8 ak = ldfrag(&Ks[n*16 + fr][ks*32 + fg]);
        acc = __builtin_amdgcn_mfma_f32_16x16x32_bf16(ak, qf[ks], acc, 0, 0, 0);
      }
      #pragma unroll
      for (int i = 0; i < 4; ++i) sv[n][i] = acc[i];
    }
    if (kt == qb) {                  // causal mask only on diagonal tile
      const int qrow = w*16 + fr;
      #pragma unroll
      for (int n = 0; n < 4; ++n)
        #pragma unroll
        for (int i = 0; i < 4; ++i)
          if (n*16 + fg + i > qrow) sv[n][i] = -__builtin_inff();
    }
    // row reduce: in-lane 16 values + 2 shfl across g-groups
    float rm = -__builtin_inff();
    #pragma unroll
    for (int n = 0; n < 4; ++n)
      #pragma unroll
      for (int i = 0; i < 4; ++i) rm = fmaxf(rm, sv[n][i]);
    rm = fmaxf(rm, __shfl_xor(rm, 16));
    rm = fmaxf(rm, __shfl_xor(rm, 32));
    float mnew = fmaxf(m_, rm);
    float sc = __expf(m_ - mnew);
    m_ = mnew;
    float rs = 0.f;
    float pvv[4][4];
    #pragma unroll
    for (int n = 0; n < 4; ++n)
      #pragma unroll
      for (int i = 0; i < 4; ++i) {
        float p = __expf(sv[n][i] - mnew);
        pvv[n][i] = p; rs += p;
      }
    rs += __shfl_xor(rs, 16);
    rs += __shfl_xor(rs, 32);
    l_ = l_ * sc + rs;
    // redistribute rescale to O rows (q = fg+i)
    float scs[4];
    #pragma unroll
    for (int i = 0; i < 4; ++i) scs[i] = __shfl(sc, fg + i);
    #pragma unroll
    for (int dn = 0; dn < 4; ++dn)
      #pragma unroll
      for (int i = 0; i < 4; ++i) o_[dn][i] *= scs[i];
    // pack P (already in PV A-frag layout)
    bf16x8 pa[2];
    #pragma unroll
    for (int ks = 0; ks < 2; ++ks)
      #pragma unroll
      for (int n2 = 0; n2 < 2; ++n2)
        #pragma unroll
        for (int i = 0; i < 4; ++i)
          pa[ks][n2*4 + i] = (__bf16)pvv[2*ks + n2][i];

    // O += P @ V
    #pragma unroll
    for (int ks = 0; ks < 2; ++ks)
      #pragma unroll
      for (int dn = 0; dn < 4; ++dn) {
        bf16x8 bv = ldfrag(&Vs[dn*16 + fr][ks*32 + fg]);
        o_[dn] = __builtin_amdgcn_mfma_f32_16x16x32_bf16(pa[ks], bv, o_[dn], 0, 0, 0);
      }
  }

  // epilogue: write normalized O (bf16) + (m,l)
  const size_t plane = ((size_t)(c*2 + st) * 16 + h) * 2048;
  float inv = (l_ > 0.f) ? 1.f / l_ : 0.f;
  float invi[4];
  #pragma unroll
  for (int i = 0; i < 4; ++i) invi[i] = __shfl(inv, fg + i);
  #pragma unroll
  for (int dn = 0; dn < 4; ++dn)
    #pragma unroll
    for (int i = 0; i < 4; ++i) {
      int row = qb*64 + w*16 + fg + i;
      On[(plane + row) * 64 + dn*16 + fr] = f2bf(o_[dn][i] * invi[i]);
    }
  if (lane < 16) {
    int row = qb*64 + w*16 + fr;
    Ml[plane + row]          = m_;
    Ml[131072 + plane + row] = l_;
  }
}

// ---------------- merge chunks + differential combine + LN partials ----------------
__global__ __launch_bounds__(256) void merge_stats(const ushort* __restrict__ On,
                                                   const float* __restrict__ Ml,
                                                   const float* __restrict__ lamp,
                                                   float* __restrict__ Yf,
                                                   float* __restrict__ part) {
  const int h = blockIdx.x & 15, sl = blockIdx.x >> 4;
  const float lam = *lamp;
  float s = 0.f, s2 = 0.f;
  for (int e = threadIdx.x; e < 2048; e += 256) {   // 128 rows x 16 float4-of-d
    int row = sl * 128 + (e >> 4);
    int d4  = (e & 15) * 4;
    float o[2][4];
    #pragma unroll
    for (int st = 0; st < 2; ++st) {
      size_t p0 = ((size_t)st * 16 + h) * 2048 + row;        // chunk 0
      size_t p1 = ((size_t)(2 + st) * 16 + h) * 2048 + row;  // chunk 1
      float m0 = Ml[p0], l0 = Ml[131072 + p0];
      float m1 = Ml[p1], l1 = Ml[131072 + p1];
      float M  = fmaxf(m0, m1);
      float w0 = (l0 > 0.f) ? l0 * __expf(m0 - M) : 0.f;
      float w1 = (l1 > 0.f) ? l1 * __expf(m1 - M) : 0.f;
      float inv = 1.f / (w0 + w1);
      w0 *= inv; w1 *= inv;
      ushort4 a = *(const ushort4*)(On + p0 * 64 + d4);
      ushort4 b = *(const ushort4*)(On + p1 * 64 + d4);
      o[st][0] = w0 * bf2f(a.x) + w1 * bf2f(b.x);
      o[st][1] = w0 * bf2f(a.y) + w1 * bf2f(b.y);
      o[st][2] = w0 * bf2f(a.z) + w1 * bf2f(b.z);
      o[st][3] = w0 * bf2f(a.w) + w1 * bf2f(b.w);
    }
    float4 v;
    v.x = o[0][0] - lam * o[1][0];
    v.y = o[0][1] - lam * o[1][1];
    v.z = o[0][2] - lam * o[1][2];
    v.w = o[0][3] - lam * o[1][3];
    s  += v.x + v.y + v.z + v.w;
    s2 += v.x*v.x + v.y*v.y + v.z*v.z + v.w*v.w;
    *(float4*)(Yf + (size_t)row * DIM + h * 64 + d4) = v;
  }
  #pragma unroll
  for (int off = 32; off >= 1; off >>= 1) { s += __shfl_down(s, off); s2 += __shfl_down(s2, off); }
  __shared__ float sb[8];
  int wv = threadIdx.x >> 6, lane = threadIdx.x & 63;
  if (lane == 0) { sb[wv] = s; sb[4 + wv] = s2; }
  __syncthreads();
  if (threadIdx.x == 0) {
    part[blockIdx.x]       = sb[0] + sb[1] + sb[2] + sb[3];
    part[256 + blockIdx.x] = sb[4] + sb[5] + sb[6] + sb[7];
  }
}

__global__ void stats_final(const float* __restrict__ part, float* __restrict__ stat) {
  int hh = threadIdx.x;
  if (hh < 16) {
    float S = 0.f, S2 = 0.f;
    #pragma unroll
    for (int sl = 0; sl < 16; ++sl) { S += part[sl*16 + hh]; S2 += part[256 + sl*16 + hh]; }
    const float N = (float)(T_SEQ * HDIM);
    float mean = S / N;
    float var  = S2 / N - mean * mean;
    stat[hh]      = mean;
    stat[16 + hh] = rsqrtf(var + 1e-5f);
  }
}

__global__ void norm_cvt(const float* __restrict__ Y, const float* __restrict__ stats,
                         ushort* __restrict__ Yb) {
  int idx = blockIdx.x * 256 + threadIdx.x;
  int col = idx & (DIM - 1);
  int h = col >> 6;
  float v = (Y[idx] - stats[h]) * stats[16 + h] * ONE_MINUS_LI;
  Yb[idx] = f2bf(v);
}

// ---------------- launch ----------------
extern "C" void kernel_launch(void* const* d_in, const int* in_sizes, int n_in,
                              void* d_out, int out_size, void* d_ws, size_t ws_size,
                              hipStream_t stream) {
  const float* x   = (const float*)d_in[0];
  const float* fc  = (const float*)d_in[1];
  const float* fs  = (const float*)d_in[2];
  const float* wq  = (const float*)d_in[3];
  const float* wk  = (const float*)d_in[4];
  const float* wv  = (const float*)d_in[5];
  const float* wo  = (const float*)d_in[6];
  const float* lq1 = (const float*)d_in[7];
  const float* lk1 = (const float*)d_in[8];
  const float* lq2 = (const float*)d_in[9];
  const float* lk2 = (const float*)d_in[10];
  float* out = (float*)d_out;

  char* ws = (char*)d_ws;
  // Liveness plan:
  //  phase1 (cvt/gemm1/reorg): Wob | xb | Wb | QKVb | Qr Kr Vt
  //  phase2 (attn):            Wob | On (over xb/Wb/QKV head) | Ml | Qr Kr Vt
  //  phase3 (merge..gemm2):    Wob | On | Ml | Yf (over QKV tail + dead Qr head) | Yb
  const size_t OFF_WOB  = 0;                 // 2 MB, live till end
  const size_t OFF_XB   = 2097152;           // 4 MB, dead after gemm1
  const size_t OFF_WB   = 6291456;           // 7 MB, dead after gemm1
  const size_t OFF_QKV  = 13631488;          // 14.68 MB, dead after reorg
  const size_t OFF_QR   = 28311552;          // 8 MB, dead after attn
  const size_t OFF_KR   = 36700160;          // 4 MB, dead after attn
  const size_t OFF_VT   = 40894464;          // 2 MB, dead after attn
  const size_t OFF_ON   = 2097152;           // 16 MB (bf16), written by attn
  const size_t OFF_ML   = 18874368;          // 1 MB fp32 m+l
  const size_t OFF_Y    = 20971520;          // 8 MB, written by merge (Qr head dead)
  const size_t OFF_YB   = 42991616;          // 4 MB
  const size_t OFF_ST   = 47185920;          // stats + lam + partials

  ushort* xb   = (ushort*)(ws + OFF_XB);
  ushort* Wb   = (ushort*)(ws + OFF_WB);
  ushort* Wob  = (ushort*)(ws + OFF_WOB);
  ushort* QKVb = (ushort*)(ws + OFF_QKV);
  ushort* Qr   = (ushort*)(ws + OFF_QR);
  ushort* Kr   = (ushort*)(ws + OFF_KR);
  ushort* Vt   = (ushort*)(ws + OFF_VT);
  ushort* On   = (ushort*)(ws + OFF_ON);
  float*  Ml   = (float*)(ws + OFF_ML);
  float*  Yf   = (float*)(ws + OFF_Y);
  ushort* Yb   = (ushort*)(ws + OFF_YB);
  float*  stat = (float*)(ws + OFF_ST);
  float*  lamp = stat + 32;
  float*  part = stat + 64;                  // 512 floats

  cvt_all<<<6656, 256, 0, stream>>>(x, wq, wk, wv, wo, xb, Wb, Wob);
  lam_kernel<<<1, 64, 0, stream>>>(lq1, lk1, lq2, lk2, lamp);

  gemm_bt<1><<<dim3(QKVN/128, T_SEQ/128), 256, 0, stream>>>(xb, Wb, QKVb, T_SEQ, QKVN, DIM);

  reorg<<<3584, 256, 0, stream>>>(QKVb, Qr, Kr, Vt, fc, fs);

  attn_kernel<<<2048, 256, 0, stream>>>(Qr, Kr, Vt, On, Ml);

  merge_stats<<<256, 256, 0, stream>>>(On, Ml, lamp, Yf, part);
  stats_final<<<1, 64, 0, stream>>>(part, stat);
  norm_cvt<<<8192, 256, 0, stream>>>(Yf, stat, Yb);

  gemm_bt<0><<<dim3(DIM/128, T_SEQ/128), 256, 0, stream>>>(Yb, Wob, out, T_SEQ, DIM, DIM);
}

// Round 7
// 239.934 us; speedup vs baseline: 1.7409x; 1.7409x over previous
//
#include <hip/hip_runtime.h>
#include <hip/hip_bf16.h>
#include <cstdint>

#define T_SEQ 2048
#define DIM   1024
#define NHEAD 16
#define NKVH  8
#define HDIM  64
#define QKVN  3584   // 2048 (q) + 1024 (k) + 512 (v)

static constexpr float LAMBDA_INIT_F = 0.3555090675909693f;
static constexpr float ONE_MINUS_LI  = 0.6444909324090307f;
static constexpr float QSCALE_EXP2   = 0.1803368801111144f;  // 0.125 * log2(e)

typedef __bf16 bf16x8 __attribute__((ext_vector_type(8)));
typedef float  f32x4  __attribute__((ext_vector_type(4)));

static __device__ __forceinline__ ushort f2bf(float f) {
  union { float f; uint32_t u; } x; x.f = f;
  uint32_t u = x.u;
  uint32_t r = (u + 0x7fffu + ((u >> 16) & 1u)) >> 16;
  return (ushort)r;
}
static __device__ __forceinline__ float bf2f(ushort u) {
  union { uint32_t u; float f; } x; x.u = ((uint32_t)u) << 16; return x.f;
}
static __device__ __forceinline__ f32x4 zero4() {
  f32x4 z = {0.f, 0.f, 0.f, 0.f}; return z;
}
// Load one 8-element A/B fragment for mfma_f32_16x16x32_bf16.
// Per-lane k layout: halves at k = 4*(lane>>4) and k = 16 + 4*(lane>>4).
static __device__ __forceinline__ bf16x8 ldfrag(const ushort* p) {
  union { bf16x8 v; uint2 u[2]; } r;
  r.u[0] = *(const uint2*)(p);
  r.u[1] = *(const uint2*)(p + 16);
  return r.v;
}
// async global->LDS, 16B per lane; lds dest = base + lane*16 (wave-uniform base)
static __device__ __forceinline__ void gll16(const ushort* g, ushort* l) {
  __builtin_amdgcn_global_load_lds(
      (const __attribute__((address_space(1))) uint32_t*)g,
      (__attribute__((address_space(3))) uint32_t*)l, 16, 0, 0);
}

// ---------------- fused fp32->bf16 conversion (vectorized x4) ----------------
__global__ void cvt_all(const float* __restrict__ x,  const float* __restrict__ wq,
                        const float* __restrict__ wk, const float* __restrict__ wv,
                        const float* __restrict__ wo,
                        ushort* __restrict__ xb, ushort* __restrict__ Wb,
                        ushort* __restrict__ Wob) {
  int g = (blockIdx.x * 256 + threadIdx.x) * 4;   // < 6815744
  float4 v; ushort* dst;
  if (g < 2097152) {
    v = *(const float4*)(x + g); dst = xb + g;
  } else if (g < 5767168) {
    int j = g - 2097152;
    const float* src = (j < 2097152) ? (wq + j)
                     : (j < 3145728) ? (wk + (j - 2097152))
                                     : (wv + (j - 3145728));
    v = *(const float4*)src; dst = Wb + j;
  } else {
    int j = g - 5767168;
    v = *(const float4*)(wo + j); dst = Wob + j;
  }
  ushort4 o4;
  o4.x = f2bf(v.x); o4.y = f2bf(v.y); o4.z = f2bf(v.z); o4.w = f2bf(v.w);
  *(ushort4*)dst = o4;
}

__global__ void lam_kernel(const float* __restrict__ lq1, const float* __restrict__ lk1,
                           const float* __restrict__ lq2, const float* __restrict__ lk2,
                           float* __restrict__ lam) {
  int lane = threadIdx.x;  // 64 threads
  float p1 = lq1[lane] * lk1[lane];
  float p2 = lq2[lane] * lk2[lane];
  #pragma unroll
  for (int off = 32; off >= 1; off >>= 1) {
    p1 += __shfl_down(p1, off);
    p2 += __shfl_down(p2, off);
  }
  if (lane == 0) *lam = expf(p1) - expf(p2) + LAMBDA_INIT_F;
}

// ---------------- GEMM: C[M][N] = A[M][K] @ W[N][K]^T, m97 structure + T1 swizzle --
template<int BF16OUT>
__global__ __launch_bounds__(256) void gemm_bt(const ushort* __restrict__ A,
                                               const ushort* __restrict__ W,
                                               void* __restrict__ Cout,
                                               int M, int N, int K) {
  __shared__ ushort As[128 * 32];
  __shared__ ushort Ws[128 * 32];
  const int tid  = threadIdx.x;
  const int lane = tid & 63;
  const int w    = tid >> 6;
  const int wr   = w >> 1, wc = w & 1;
  // XCD-aware bijective swizzle (nwg % 8 == 0), column-major linearization
  const int nwg = gridDim.x * gridDim.y;
  int id  = blockIdx.x * gridDim.y + blockIdx.y;
  int sw  = (id & 7) * (nwg >> 3) + (id >> 3);
  const int bm = (sw % gridDim.y) * 128;
  const int bn = (sw / gridDim.y) * 128;
  const int fr   = lane & 15;
  const int fg   = (lane >> 4) * 4;

  f32x4 acc[4][4];
  #pragma unroll
  for (int m = 0; m < 4; ++m)
    #pragma unroll
    for (int n = 0; n < 4; ++n) acc[m][n] = zero4();

  const int col  = (lane & 3) * 8;
  const int row0 = w * 16 + (lane >> 2);
  const int row1 = row0 + 64;
  const ushort* ga0 = A + (size_t)(bm + row0) * K + col;
  const ushort* ga1 = A + (size_t)(bm + row1) * K + col;
  const ushort* gw0 = W + (size_t)(bn + row0) * K + col;
  const ushort* gw1 = W + (size_t)(bn + row1) * K + col;
  ushort* la0 = As + (w * 512);
  ushort* la1 = As + (w * 512) + 2048;
  ushort* lw0 = Ws + (w * 512);
  ushort* lw1 = Ws + (w * 512) + 2048;

  for (int k0 = 0; k0 < K; k0 += 32) {
    gll16(ga0 + k0, la0);
    gll16(ga1 + k0, la1);
    gll16(gw0 + k0, lw0);
    gll16(gw1 + k0, lw1);
    __syncthreads();
    bf16x8 af[4], bfr[4];
    #pragma unroll
    for (int m = 0; m < 4; ++m) af[m]  = ldfrag(&As[(wr*64 + m*16 + fr) * 32 + fg]);
    #pragma unroll
    for (int n = 0; n < 4; ++n) bfr[n] = ldfrag(&Ws[(wc*64 + n*16 + fr) * 32 + fg]);
    #pragma unroll
    for (int m = 0; m < 4; ++m)
      #pragma unroll
      for (int n = 0; n < 4; ++n)
        acc[m][n] = __builtin_amdgcn_mfma_f32_16x16x32_bf16(af[m], bfr[n], acc[m][n], 0, 0, 0);
    __syncthreads();
  }

  #pragma unroll
  for (int m = 0; m < 4; ++m)
    #pragma unroll
    for (int n = 0; n < 4; ++n)
      #pragma unroll
      for (int i = 0; i < 4; ++i) {
        int row = bm + wr*64 + m*16 + fg + i;
        int colg = bn + wc*64 + n*16 + fr;
        float v = acc[m][n][i];
        if (BF16OUT) ((ushort*)Cout)[(size_t)row * N + colg] = f2bf(v);
        else         ((float*)Cout)[(size_t)row * N + colg]  = v;
      }
}

// ---------------- fused RoPE Q, RoPE K, pack V (vectorized) ----------------
// Q is scaled by 0.125*log2(e) so attention works in the exp2 domain.
__global__ void reorg(const ushort* __restrict__ QKV, ushort* __restrict__ Qr,
                      ushort* __restrict__ Kr, ushort* __restrict__ Vt,
                      const float* __restrict__ fc, const float* __restrict__ fs) {
  int idx = blockIdx.x * 256 + threadIdx.x;   // < 917504
  if (idx < 786432) {
    // RoPE, 4 interleaved pairs (8 bf16) per thread
    int nheads, col_off; ushort* dst; float scale; int id;
    if (idx < 524288) { id = idx * 4; nheads = NHEAD; col_off = 0; dst = Qr; scale = QSCALE_EXP2; }
    else { id = (idx - 524288) * 4; nheads = NKVH; col_off = 2048; dst = Kr; scale = 1.0f; }
    int per_t = nheads * 64;
    int t  = id / per_t;
    int r  = id - t * per_t;
    int hh = r >> 6;
    int c2 = (r >> 5) & 1;
    int j  = r & 31;                      // multiple of 4
    int cl = col_off + hh * 128 + c2 * 64 + 2 * j;
    uint4 raw = *(const uint4*)(QKV + (size_t)t * QKVN + cl);
    const ushort* rp = (const ushort*)&raw;
    float c4[4], s4[4];
    *(float4*)c4 = *(const float4*)(fc + t * 32 + j);
    *(float4*)s4 = *(const float4*)(fs + t * 32 + j);
    ushort outv[8];
    #pragma unroll
    for (int p = 0; p < 4; ++p) {
      float rv = bf2f(rp[2*p]), iv = bf2f(rp[2*p + 1]);
      outv[2*p]     = f2bf((rv * c4[p] - iv * s4[p]) * scale);
      outv[2*p + 1] = f2bf((rv * s4[p] + iv * c4[p]) * scale);
    }
    size_t o = ((size_t)(c2 * nheads + hh) * T_SEQ + t) * HDIM + 2 * j;
    *(uint4*)(dst + o) = *(const uint4*)outv;
  } else {
    // V transpose: 8 t-consecutive elems -> one contiguous store
    int id = (idx - 786432) * 8;           // < 1048576
    int t = id & (T_SEQ - 1);              // multiple of 8
    int rest = id >> 11;                   // kh*64 + d
    ushort outv[8];
    #pragma unroll
    for (int p = 0; p < 8; ++p) outv[p] = QKV[(size_t)(t + p) * QKVN + 3072 + rest];
    *(uint4*)(Vt + (size_t)rest * T_SEQ + t) = *(const uint4*)outv;
  }
}

// ---------------- flash attention (R2 structure): both streams per block ----------
// 512 blocks = (head, qb); 4 waves x 16 q-rows, each wave does both streams.
// Swapped QK^T keeps P in-register; exp2-domain softmax with defer-max (THR=8).
// Epilogue: differential combine, direct Yf write, fused LN partial sums.
__global__ __launch_bounds__(256) void attn_kernel(const ushort* __restrict__ Qr,
                                                   const ushort* __restrict__ Kr,
                                                   const ushort* __restrict__ Vt,
                                                   const float* __restrict__ lamp,
                                                   float* __restrict__ Yf,
                                                   float* __restrict__ part) {
  const int bx = blockIdx.x;          // 0..511
  const int h  = bx & 15;
  const int jb = bx >> 4;             // 0..31; pair (jb, jb+16) sums to 32 tiles
  const int qb = (jb < 16) ? (31 - jb) : (jb - 16);
  const int kh = h >> 1;
  const int tid = threadIdx.x;
  const int lane = tid & 63;
  const int w   = tid >> 6;
  const int fr  = lane & 15;
  const int fg  = (lane >> 4) * 4;

  __shared__ ushort Ks[2][64][72];
  __shared__ ushort Vs[64][72];      // [d][s]
  __shared__ float sb[8];

  // Q fragments (pre-scaled 0.125*log2e); B-operand (col = q row)
  bf16x8 qf[2][2];
  {
    const int row = qb * 64 + w * 16 + fr;
    #pragma unroll
    for (int st = 0; st < 2; ++st) {
      const ushort* qp = Qr + ((size_t)(st * NHEAD + h) * T_SEQ + row) * HDIM;
      #pragma unroll
      for (int ks = 0; ks < 2; ++ks) qf[st][ks] = ldfrag(qp + ks * 32 + fg);
    }
  }

  float m_[2], l_[2];
  f32x4 o_[2][4];
  #pragma unroll
  for (int st = 0; st < 2; ++st) {
    m_[st] = -__builtin_inff(); l_[st] = 0.f;
    #pragma unroll
    for (int dn = 0; dn < 4; ++dn) o_[st][dn] = zero4();
  }

  // K/V prefetch registers
  const int srow = tid >> 2, scol = (tid & 3) * 16;
  uint4 kpre[2][2], vpre[2];
  {
    #pragma unroll
    for (int c2 = 0; c2 < 2; ++c2) {
      const ushort* src = Kr + ((size_t)(c2 * NKVH + kh) * T_SEQ + srow) * HDIM + scol;
      kpre[c2][0] = *(const uint4*)src;
      kpre[c2][1] = *(const uint4*)(src + 8);
    }
    const ushort* vsrc = Vt + (size_t)(kh * 64 + srow) * T_SEQ + scol;
    vpre[0] = *(const uint4*)vsrc;
    vpre[1] = *(const uint4*)(vsrc + 8);
  }

  for (int kt = 0; kt <= qb; ++kt) {
    __syncthreads();                 // prev iteration's LDS reads complete
    #pragma unroll
    for (int c2 = 0; c2 < 2; ++c2) {
      *(uint4*)&Ks[c2][srow][scol]     = kpre[c2][0];
      *(uint4*)&Ks[c2][srow][scol + 8] = kpre[c2][1];
    }
    *(uint4*)&Vs[srow][scol]     = vpre[0];
    *(uint4*)&Vs[srow][scol + 8] = vpre[1];
    if (kt < qb) {
      const int nb = (kt + 1) * 64;
      #pragma unroll
      for (int c2 = 0; c2 < 2; ++c2) {
        const ushort* src = Kr + ((size_t)(c2 * NKVH + kh) * T_SEQ + nb + srow) * HDIM + scol;
        kpre[c2][0] = *(const uint4*)src;
        kpre[c2][1] = *(const uint4*)(src + 8);
      }
      const ushort* vsrc = Vt + (size_t)(kh * 64 + srow) * T_SEQ + nb + scol;
      vpre[0] = *(const uint4*)vsrc;
      vpre[1] = *(const uint4*)(vsrc + 8);
    }
    __syncthreads();                 // staging visible

    bf16x8 pa[2][2];                 // P fragments (A-operand for PV), per stream
    #pragma unroll
    for (int st = 0; st < 2; ++st) {
      // S^T tile: mfma(K rows, Q cols) -> lane holds q=fr, keys n*16+fg+i
      float sv[4][4];
      #pragma unroll
      for (int n = 0; n < 4; ++n) {
        f32x4 acc = zero4();
        #pragma unroll
        for (int ks = 0; ks < 2; ++ks) {
          bf16x8 ak = ldfrag(&Ks[st][n*16 + fr][ks*32 + fg]);
          acc = __builtin_amdgcn_mfma_f32_16x16x32_bf16(ak, qf[st][ks], acc, 0, 0, 0);
        }
        #pragma unroll
        for (int i = 0; i < 4; ++i) sv[n][i] = acc[i];
      }
      if (kt == qb) {                // causal mask only on diagonal tile
        const int qrow = w*16 + fr;  // q - kvb
        #pragma unroll
        for (int n = 0; n < 4; ++n)
          #pragma unroll
          for (int i = 0; i < 4; ++i)
            if (n*16 + fg + i > qrow) sv[n][i] = -__builtin_inff();
      }
      // row max: in-lane 16 values + 2 shfl across g-groups
      float rm = -__builtin_inff();
      #pragma unroll
      for (int n = 0; n < 4; ++n)
        #pragma unroll
        for (int i = 0; i < 4; ++i) rm = fmaxf(rm, sv[n][i]);
      rm = fmaxf(rm, __shfl_xor(rm, 16));
      rm = fmaxf(rm, __shfl_xor(rm, 32));
      // defer-max: skip rescale when bounded (exp2 domain, THR=8 -> P <= 256)
      if (!__all(rm <= m_[st] + 8.f)) {
        float mnew = fmaxf(m_[st], rm);
        float sc = __builtin_amdgcn_exp2f(m_[st] - mnew);
        m_[st] = mnew;
        l_[st] *= sc;
        float scs[4];
        #pragma unroll
        for (int i = 0; i < 4; ++i) scs[i] = __shfl(sc, fg + i);
        #pragma unroll
        for (int dn = 0; dn < 4; ++dn)
          #pragma unroll
          for (int i = 0; i < 4; ++i) o_[st][dn][i] *= scs[i];
      }
      float rs = 0.f;
      #pragma unroll
      for (int n = 0; n < 4; ++n)
        #pragma unroll
        for (int i = 0; i < 4; ++i) {
          float p = __builtin_amdgcn_exp2f(sv[n][i] - m_[st]);
          sv[n][i] = p; rs += p;
        }
      rs += __shfl_xor(rs, 16);
      rs += __shfl_xor(rs, 32);
      l_[st] += rs;
      // pack P (already in PV A-frag layout: ks half = key blocks 2ks, 2ks+1)
      #pragma unroll
      for (int ks = 0; ks < 2; ++ks)
        #pragma unroll
        for (int n2 = 0; n2 < 2; ++n2)
          #pragma unroll
          for (int i = 0; i < 4; ++i)
            pa[st][ks][n2*4 + i] = (__bf16)sv[2*ks + n2][i];
    }

    // O += P @ V (shared V fragment feeds both streams)
    #pragma unroll
    for (int ks = 0; ks < 2; ++ks)
      #pragma unroll
      for (int dn = 0; dn < 4; ++dn) {
        bf16x8 bv = ldfrag(&Vs[dn*16 + fr][ks*32 + fg]);
        o_[0][dn] = __builtin_amdgcn_mfma_f32_16x16x32_bf16(pa[0][ks], bv, o_[0][dn], 0, 0, 0);
        o_[1][dn] = __builtin_amdgcn_mfma_f32_16x16x32_bf16(pa[1][ks], bv, o_[1][dn], 0, 0, 0);
      }
  }

  // epilogue: differential combine + Yf write + LN partial sums
  const float lam = *lamp;
  float inv0 = __builtin_amdgcn_rcpf(l_[0]);
  float inv1 = __builtin_amdgcn_rcpf(l_[1]);
  float i0[4], i1[4];
  #pragma unroll
  for (int i = 0; i < 4; ++i) {
    i0[i] = __shfl(inv0, fg + i);
    i1[i] = __shfl(inv1, fg + i);
  }
  float s = 0.f, s2 = 0.f;
  #pragma unroll
  for (int dn = 0; dn < 4; ++dn)
    #pragma unroll
    for (int i = 0; i < 4; ++i) {
      int row = qb*64 + w*16 + fg + i;
      int col = h*64 + dn*16 + fr;
      float v = o_[0][dn][i] * i0[i] - lam * o_[1][dn][i] * i1[i];
      Yf[(size_t)row * DIM + col] = v;
      s += v; s2 += v * v;
    }
  #pragma unroll
  for (int off = 1; off <= 32; off <<= 1) {
    s  += __shfl_xor(s, off);
    s2 += __shfl_xor(s2, off);
  }
  if (lane == 0) { sb[w] = s; sb[4 + w] = s2; }
  __syncthreads();
  if (tid == 0) {
    part[bx]       = sb[0] + sb[1] + sb[2] + sb[3];
    part[512 + bx] = sb[4] + sb[5] + sb[6] + sb[7];
  }
}

// ---------------- finalize per-head stats ----------------
__global__ void stats_final(const float* __restrict__ part, float* __restrict__ stat) {
  int hh = threadIdx.x;
  if (hh < 16) {
    float S = 0.f, S2 = 0.f;
    #pragma unroll
    for (int j = 0; j < 32; ++j) { S += part[j*16 + hh]; S2 += part[512 + j*16 + hh]; }
    const float N = (float)(T_SEQ * HDIM);
    float mean = S / N;
    float var  = S2 / N - mean * mean;
    stat[hh]      = mean;
    stat[16 + hh] = rsqrtf(var + 1e-5f);
  }
}

__global__ void norm_cvt(const float* __restrict__ Y, const float* __restrict__ stats,
                         ushort* __restrict__ Yb) {
  int idx = (blockIdx.x * 256 + threadIdx.x) * 4;   // < T*DIM
  int col = idx & (DIM - 1);
  int h = col >> 6;
  float mean = stats[h], isd = stats[16 + h] * ONE_MINUS_LI;
  float4 v = *(const float4*)(Y + idx);
  ushort4 o4;
  o4.x = f2bf((v.x - mean) * isd);
  o4.y = f2bf((v.y - mean) * isd);
  o4.z = f2bf((v.z - mean) * isd);
  o4.w = f2bf((v.w - mean) * isd);
  *(ushort4*)(Yb + idx) = o4;
}

// ---------------- launch ----------------
extern "C" void kernel_launch(void* const* d_in, const int* in_sizes, int n_in,
                              void* d_out, int out_size, void* d_ws, size_t ws_size,
                              hipStream_t stream) {
  const float* x   = (const float*)d_in[0];
  const float* fc  = (const float*)d_in[1];
  const float* fs  = (const float*)d_in[2];
  const float* wq  = (const float*)d_in[3];
  const float* wk  = (const float*)d_in[4];
  const float* wv  = (const float*)d_in[5];
  const float* wo  = (const float*)d_in[6];
  const float* lq1 = (const float*)d_in[7];
  const float* lk1 = (const float*)d_in[8];
  const float* lq2 = (const float*)d_in[9];
  const float* lk2 = (const float*)d_in[10];
  float* out = (float*)d_out;

  char* ws = (char*)d_ws;
  const size_t OFF_WOB  = 0;                 // 2 MB, live till end
  const size_t OFF_XB   = 2097152;           // 4 MB, dead after gemm1
  const size_t OFF_WB   = 6291456;           // 7 MB, dead after gemm1
  const size_t OFF_QKV  = 13631488;          // 14.68 MB, dead after reorg
  const size_t OFF_QR   = 28311552;          // 8 MB
  const size_t OFF_KR   = 36700160;          // 4 MB
  const size_t OFF_VT   = 40894464;          // 2 MB
  const size_t OFF_Y    = 18874368;          // 8 MB over dead QKV tail
  const size_t OFF_YB   = 42991616;          // 4 MB
  const size_t OFF_ST   = 47185920;          // stats + lam + partials

  ushort* xb   = (ushort*)(ws + OFF_XB);
  ushort* Wb   = (ushort*)(ws + OFF_WB);
  ushort* Wob  = (ushort*)(ws + OFF_WOB);
  ushort* QKVb = (ushort*)(ws + OFF_QKV);
  ushort* Qr   = (ushort*)(ws + OFF_QR);
  ushort* Kr   = (ushort*)(ws + OFF_KR);
  ushort* Vt   = (ushort*)(ws + OFF_VT);
  float*  Yf   = (float*)(ws + OFF_Y);
  ushort* Yb   = (ushort*)(ws + OFF_YB);
  float*  stat = (float*)(ws + OFF_ST);
  float*  lamp = stat + 32;
  float*  part = stat + 64;                  // 1024 floats

  cvt_all<<<6656, 256, 0, stream>>>(x, wq, wk, wv, wo, xb, Wb, Wob);
  lam_kernel<<<1, 64, 0, stream>>>(lq1, lk1, lq2, lk2, lamp);

  gemm_bt<1><<<dim3(QKVN/128, T_SEQ/128), 256, 0, stream>>>(xb, Wb, QKVb, T_SEQ, QKVN, DIM);

  reorg<<<3584, 256, 0, stream>>>(QKVb, Qr, Kr, Vt, fc, fs);

  attn_kernel<<<512, 256, 0, stream>>>(Qr, Kr, Vt, lamp, Yf, part);

  stats_final<<<1, 64, 0, stream>>>(part, stat);
  norm_cvt<<<2048, 256, 0, stream>>>(Yf, stat, Yb);

  gemm_bt<0><<<dim3(DIM/128, T_SEQ/128), 256, 0, stream>>>(Yb, Wob, out, T_SEQ, DIM, DIM);
}

// Round 8
// 239.291 us; speedup vs baseline: 1.7456x; 1.0027x over previous
//
#include <hip/hip_runtime.h>
#include <hip/hip_bf16.h>
#include <cstdint>

#define T_SEQ 2048
#define DIM   1024
#define NHEAD 16
#define NKVH  8
#define HDIM  64
#define QKVN  3584   // 2048 (q) + 1024 (k) + 512 (v)

static constexpr float LAMBDA_INIT_F = 0.3555090675909693f;
static constexpr float ONE_MINUS_LI  = 0.6444909324090307f;
static constexpr float QSCALE_EXP2   = 0.1803368801111144f;  // 0.125 * log2(e)

typedef __bf16 bf16x8 __attribute__((ext_vector_type(8)));
typedef float  f32x4  __attribute__((ext_vector_type(4)));

static __device__ __forceinline__ ushort f2bf(float f) {
  union { float f; uint32_t u; } x; x.f = f;
  uint32_t u = x.u;
  uint32_t r = (u + 0x7fffu + ((u >> 16) & 1u)) >> 16;
  return (ushort)r;
}
static __device__ __forceinline__ float bf2f(ushort u) {
  union { uint32_t u; float f; } x; x.u = ((uint32_t)u) << 16; return x.f;
}
static __device__ __forceinline__ f32x4 zero4() {
  f32x4 z = {0.f, 0.f, 0.f, 0.f}; return z;
}
// Load one 8-element A/B fragment for mfma_f32_16x16x32_bf16.
// Per-lane k layout: halves at k = 4*(lane>>4) and k = 16 + 4*(lane>>4).
static __device__ __forceinline__ bf16x8 ldfrag(const ushort* p) {
  union { bf16x8 v; uint2 u[2]; } r;
  r.u[0] = *(const uint2*)(p);
  r.u[1] = *(const uint2*)(p + 16);
  return r.v;
}
// async global->LDS, 16B per lane; lds dest = base + lane*16 (wave-uniform base)
static __device__ __forceinline__ void gll16(const ushort* g, ushort* l) {
  __builtin_amdgcn_global_load_lds(
      (const __attribute__((address_space(1))) uint32_t*)g,
      (__attribute__((address_space(3))) uint32_t*)l, 16, 0, 0);
}

// ---------------- fused fp32->bf16 conversion (vectorized x4) ----------------
__global__ void cvt_all(const float* __restrict__ x,  const float* __restrict__ wq,
                        const float* __restrict__ wk, const float* __restrict__ wv,
                        const float* __restrict__ wo,
                        ushort* __restrict__ xb, ushort* __restrict__ Wb,
                        ushort* __restrict__ Wob) {
  int g = (blockIdx.x * 256 + threadIdx.x) * 4;   // < 6815744
  float4 v; ushort* dst;
  if (g < 2097152) {
    v = *(const float4*)(x + g); dst = xb + g;
  } else if (g < 5767168) {
    int j = g - 2097152;
    const float* src = (j < 2097152) ? (wq + j)
                     : (j < 3145728) ? (wk + (j - 2097152))
                                     : (wv + (j - 3145728));
    v = *(const float4*)src; dst = Wb + j;
  } else {
    int j = g - 5767168;
    v = *(const float4*)(wo + j); dst = Wob + j;
  }
  ushort4 o4;
  o4.x = f2bf(v.x); o4.y = f2bf(v.y); o4.z = f2bf(v.z); o4.w = f2bf(v.w);
  *(ushort4*)dst = o4;
}

__global__ void lam_kernel(const float* __restrict__ lq1, const float* __restrict__ lk1,
                           const float* __restrict__ lq2, const float* __restrict__ lk2,
                           float* __restrict__ lam) {
  int lane = threadIdx.x;  // 64 threads
  float p1 = lq1[lane] * lk1[lane];
  float p2 = lq2[lane] * lk2[lane];
  #pragma unroll
  for (int off = 32; off >= 1; off >>= 1) {
    p1 += __shfl_down(p1, off);
    p2 += __shfl_down(p2, off);
  }
  if (lane == 0) *lam = expf(p1) - expf(p2) + LAMBDA_INIT_F;
}

// ---------------- GEMM: C[M][N] = A[M][K] @ W[N][K]^T, m97 structure + T1 swizzle --
template<int BF16OUT>
__global__ __launch_bounds__(256) void gemm_bt(const ushort* __restrict__ A,
                                               const ushort* __restrict__ W,
                                               void* __restrict__ Cout,
                                               int M, int N, int K) {
  __shared__ ushort As[128 * 32];
  __shared__ ushort Ws[128 * 32];
  const int tid  = threadIdx.x;
  const int lane = tid & 63;
  const int w    = tid >> 6;
  const int wr   = w >> 1, wc = w & 1;
  // XCD-aware bijective swizzle (nwg % 8 == 0), column-major linearization
  const int nwg = gridDim.x * gridDim.y;
  int id  = blockIdx.x * gridDim.y + blockIdx.y;
  int sw  = (id & 7) * (nwg >> 3) + (id >> 3);
  const int bm = (sw % gridDim.y) * 128;
  const int bn = (sw / gridDim.y) * 128;
  const int fr   = lane & 15;
  const int fg   = (lane >> 4) * 4;

  f32x4 acc[4][4];
  #pragma unroll
  for (int m = 0; m < 4; ++m)
    #pragma unroll
    for (int n = 0; n < 4; ++n) acc[m][n] = zero4();

  const int col  = (lane & 3) * 8;
  const int row0 = w * 16 + (lane >> 2);
  const int row1 = row0 + 64;
  const ushort* ga0 = A + (size_t)(bm + row0) * K + col;
  const ushort* ga1 = A + (size_t)(bm + row1) * K + col;
  const ushort* gw0 = W + (size_t)(bn + row0) * K + col;
  const ushort* gw1 = W + (size_t)(bn + row1) * K + col;
  ushort* la0 = As + (w * 512);
  ushort* la1 = As + (w * 512) + 2048;
  ushort* lw0 = Ws + (w * 512);
  ushort* lw1 = Ws + (w * 512) + 2048;

  for (int k0 = 0; k0 < K; k0 += 32) {
    gll16(ga0 + k0, la0);
    gll16(ga1 + k0, la1);
    gll16(gw0 + k0, lw0);
    gll16(gw1 + k0, lw1);
    __syncthreads();
    bf16x8 af[4], bfr[4];
    #pragma unroll
    for (int m = 0; m < 4; ++m) af[m]  = ldfrag(&As[(wr*64 + m*16 + fr) * 32 + fg]);
    #pragma unroll
    for (int n = 0; n < 4; ++n) bfr[n] = ldfrag(&Ws[(wc*64 + n*16 + fr) * 32 + fg]);
    #pragma unroll
    for (int m = 0; m < 4; ++m)
      #pragma unroll
      for (int n = 0; n < 4; ++n)
        acc[m][n] = __builtin_amdgcn_mfma_f32_16x16x32_bf16(af[m], bfr[n], acc[m][n], 0, 0, 0);
    __syncthreads();
  }

  #pragma unroll
  for (int m = 0; m < 4; ++m)
    #pragma unroll
    for (int n = 0; n < 4; ++n)
      #pragma unroll
      for (int i = 0; i < 4; ++i) {
        int row = bm + wr*64 + m*16 + fg + i;
        int colg = bn + wc*64 + n*16 + fr;
        float v = acc[m][n][i];
        if (BF16OUT) ((ushort*)Cout)[(size_t)row * N + colg] = f2bf(v);
        else         ((float*)Cout)[(size_t)row * N + colg]  = v;
      }
}

// ---------------- fused RoPE Q, RoPE K, pack V (vectorized) ----------------
// Q is scaled by 0.125*log2(e) so attention works in the exp2 domain.
__global__ void reorg(const ushort* __restrict__ QKV, ushort* __restrict__ Qr,
                      ushort* __restrict__ Kr, ushort* __restrict__ Vt,
                      const float* __restrict__ fc, const float* __restrict__ fs) {
  int idx = blockIdx.x * 256 + threadIdx.x;   // < 917504
  if (idx < 786432) {
    // RoPE, 4 interleaved pairs (8 bf16) per thread
    int nheads, col_off; ushort* dst; float scale; int id;
    if (idx < 524288) { id = idx * 4; nheads = NHEAD; col_off = 0; dst = Qr; scale = QSCALE_EXP2; }
    else { id = (idx - 524288) * 4; nheads = NKVH; col_off = 2048; dst = Kr; scale = 1.0f; }
    int per_t = nheads * 64;
    int t  = id / per_t;
    int r  = id - t * per_t;
    int hh = r >> 6;
    int c2 = (r >> 5) & 1;
    int j  = r & 31;                      // multiple of 4
    int cl = col_off + hh * 128 + c2 * 64 + 2 * j;
    uint4 raw = *(const uint4*)(QKV + (size_t)t * QKVN + cl);
    const ushort* rp = (const ushort*)&raw;
    float c4[4], s4[4];
    *(float4*)c4 = *(const float4*)(fc + t * 32 + j);
    *(float4*)s4 = *(const float4*)(fs + t * 32 + j);
    ushort outv[8];
    #pragma unroll
    for (int p = 0; p < 4; ++p) {
      float rv = bf2f(rp[2*p]), iv = bf2f(rp[2*p + 1]);
      outv[2*p]     = f2bf((rv * c4[p] - iv * s4[p]) * scale);
      outv[2*p + 1] = f2bf((rv * s4[p] + iv * c4[p]) * scale);
    }
    size_t o = ((size_t)(c2 * nheads + hh) * T_SEQ + t) * HDIM + 2 * j;
    *(uint4*)(dst + o) = *(const uint4*)outv;
  } else {
    // V transpose: 8 t-consecutive elems -> one contiguous store
    int id = (idx - 786432) * 8;           // < 1048576
    int t = id & (T_SEQ - 1);              // multiple of 8
    int rest = id >> 11;                   // kh*64 + d
    ushort outv[8];
    #pragma unroll
    for (int p = 0; p < 8; ++p) outv[p] = QKV[(size_t)(t + p) * QKVN + 3072 + rest];
    *(uint4*)(Vt + (size_t)rest * T_SEQ + t) = *(const uint4*)outv;
  }
}

// ---------------- flash attention with split-K on the heavy half -------------------
// 768 blocks: slot s = bx>>4, head h = bx&15.
//   s <  32: SPLIT blocks, qb = 31-(s>>1) in [16,31], chunk c = s&1:
//            c=0 -> tiles [0,(qb+1)/2), c=1 -> [(qb+1)/2, qb+1)  (each <= 16)
//            epilogue writes unnormalized fp32 O + (m,l) partials.
//   s >= 32: UNSPLIT blocks, qb = 47-s in [0,15]: direct Yf write + LN partials.
// Inner loop identical to R7 (swapped QK^T, exp2-domain softmax, defer-max).
__global__ __launch_bounds__(256) void attn_kernel(const ushort* __restrict__ Qr,
                                                   const ushort* __restrict__ Kr,
                                                   const ushort* __restrict__ Vt,
                                                   const float* __restrict__ lamp,
                                                   float* __restrict__ Yf,
                                                   float* __restrict__ part,
                                                   float* __restrict__ Opart,
                                                   float* __restrict__ Ml) {
  const int bx = blockIdx.x;          // 0..767
  const int h  = bx & 15;
  const int s  = bx >> 4;             // 0..47
  int qb, kt0, kt1, c;
  if (s < 32) {
    qb = 31 - (s >> 1); c = s & 1;
    int s0 = (qb + 1) >> 1;
    kt0 = c ? s0 : 0;
    kt1 = c ? (qb + 1) : s0;
  } else {
    qb = 47 - s; c = -1;
    kt0 = 0; kt1 = qb + 1;
  }
  const int kh = h >> 1;
  const int tid = threadIdx.x;
  const int lane = tid & 63;
  const int w   = tid >> 6;
  const int fr  = lane & 15;
  const int fg  = (lane >> 4) * 4;

  __shared__ ushort Ks[2][64][72];
  __shared__ ushort Vs[64][72];      // [d][s]
  __shared__ float sb[8];

  // Q fragments (pre-scaled 0.125*log2e); B-operand (col = q row)
  bf16x8 qf[2][2];
  {
    const int row = qb * 64 + w * 16 + fr;
    #pragma unroll
    for (int st = 0; st < 2; ++st) {
      const ushort* qp = Qr + ((size_t)(st * NHEAD + h) * T_SEQ + row) * HDIM;
      #pragma unroll
      for (int ks = 0; ks < 2; ++ks) qf[st][ks] = ldfrag(qp + ks * 32 + fg);
    }
  }

  float m_[2], l_[2];
  f32x4 o_[2][4];
  #pragma unroll
  for (int st = 0; st < 2; ++st) {
    m_[st] = -__builtin_inff(); l_[st] = 0.f;
    #pragma unroll
    for (int dn = 0; dn < 4; ++dn) o_[st][dn] = zero4();
  }

  // K/V prefetch registers
  const int srow = tid >> 2, scol = (tid & 3) * 16;
  uint4 kpre[2][2], vpre[2];
  {
    const int b0 = kt0 * 64;
    #pragma unroll
    for (int c2 = 0; c2 < 2; ++c2) {
      const ushort* src = Kr + ((size_t)(c2 * NKVH + kh) * T_SEQ + b0 + srow) * HDIM + scol;
      kpre[c2][0] = *(const uint4*)src;
      kpre[c2][1] = *(const uint4*)(src + 8);
    }
    const ushort* vsrc = Vt + (size_t)(kh * 64 + srow) * T_SEQ + b0 + scol;
    vpre[0] = *(const uint4*)vsrc;
    vpre[1] = *(const uint4*)(vsrc + 8);
  }

  for (int kt = kt0; kt < kt1; ++kt) {
    __syncthreads();                 // prev iteration's LDS reads complete
    #pragma unroll
    for (int c2 = 0; c2 < 2; ++c2) {
      *(uint4*)&Ks[c2][srow][scol]     = kpre[c2][0];
      *(uint4*)&Ks[c2][srow][scol + 8] = kpre[c2][1];
    }
    *(uint4*)&Vs[srow][scol]     = vpre[0];
    *(uint4*)&Vs[srow][scol + 8] = vpre[1];
    if (kt + 1 < kt1) {
      const int nb = (kt + 1) * 64;
      #pragma unroll
      for (int c2 = 0; c2 < 2; ++c2) {
        const ushort* src = Kr + ((size_t)(c2 * NKVH + kh) * T_SEQ + nb + srow) * HDIM + scol;
        kpre[c2][0] = *(const uint4*)src;
        kpre[c2][1] = *(const uint4*)(src + 8);
      }
      const ushort* vsrc = Vt + (size_t)(kh * 64 + srow) * T_SEQ + nb + scol;
      vpre[0] = *(const uint4*)vsrc;
      vpre[1] = *(const uint4*)(vsrc + 8);
    }
    __syncthreads();                 // staging visible

    bf16x8 pa[2][2];                 // P fragments (A-operand for PV), per stream
    #pragma unroll
    for (int st = 0; st < 2; ++st) {
      // S^T tile: mfma(K rows, Q cols) -> lane holds q=fr, keys n*16+fg+i
      float sv[4][4];
      #pragma unroll
      for (int n = 0; n < 4; ++n) {
        f32x4 acc = zero4();
        #pragma unroll
        for (int ks = 0; ks < 2; ++ks) {
          bf16x8 ak = ldfrag(&Ks[st][n*16 + fr][ks*32 + fg]);
          acc = __builtin_amdgcn_mfma_f32_16x16x32_bf16(ak, qf[st][ks], acc, 0, 0, 0);
        }
        #pragma unroll
        for (int i = 0; i < 4; ++i) sv[n][i] = acc[i];
      }
      if (kt == qb) {                // causal mask only on diagonal tile
        const int qrow = w*16 + fr;  // q - kvb
        #pragma unroll
        for (int n = 0; n < 4; ++n)
          #pragma unroll
          for (int i = 0; i < 4; ++i)
            if (n*16 + fg + i > qrow) sv[n][i] = -__builtin_inff();
      }
      // row max: in-lane 16 values + 2 shfl across g-groups
      float rm = -__builtin_inff();
      #pragma unroll
      for (int n = 0; n < 4; ++n)
        #pragma unroll
        for (int i = 0; i < 4; ++i) rm = fmaxf(rm, sv[n][i]);
      rm = fmaxf(rm, __shfl_xor(rm, 16));
      rm = fmaxf(rm, __shfl_xor(rm, 32));
      // defer-max: skip rescale when bounded (exp2 domain, THR=8 -> P <= 256)
      if (!__all(rm <= m_[st] + 8.f)) {
        float mnew = fmaxf(m_[st], rm);
        float sc = __builtin_amdgcn_exp2f(m_[st] - mnew);
        m_[st] = mnew;
        l_[st] *= sc;
        float scs[4];
        #pragma unroll
        for (int i = 0; i < 4; ++i) scs[i] = __shfl(sc, fg + i);
        #pragma unroll
        for (int dn = 0; dn < 4; ++dn)
          #pragma unroll
          for (int i = 0; i < 4; ++i) o_[st][dn][i] *= scs[i];
      }
      float rs = 0.f;
      #pragma unroll
      for (int n = 0; n < 4; ++n)
        #pragma unroll
        for (int i = 0; i < 4; ++i) {
          float p = __builtin_amdgcn_exp2f(sv[n][i] - m_[st]);
          sv[n][i] = p; rs += p;
        }
      rs += __shfl_xor(rs, 16);
      rs += __shfl_xor(rs, 32);
      l_[st] += rs;
      // pack P (already in PV A-frag layout: ks half = key blocks 2ks, 2ks+1)
      #pragma unroll
      for (int ks = 0; ks < 2; ++ks)
        #pragma unroll
        for (int n2 = 0; n2 < 2; ++n2)
          #pragma unroll
          for (int i = 0; i < 4; ++i)
            pa[st][ks][n2*4 + i] = (__bf16)sv[2*ks + n2][i];
    }

    // O += P @ V (shared V fragment feeds both streams)
    #pragma unroll
    for (int ks = 0; ks < 2; ++ks)
      #pragma unroll
      for (int dn = 0; dn < 4; ++dn) {
        bf16x8 bv = ldfrag(&Vs[dn*16 + fr][ks*32 + fg]);
        o_[0][dn] = __builtin_amdgcn_mfma_f32_16x16x32_bf16(pa[0][ks], bv, o_[0][dn], 0, 0, 0);
        o_[1][dn] = __builtin_amdgcn_mfma_f32_16x16x32_bf16(pa[1][ks], bv, o_[1][dn], 0, 0, 0);
      }
  }

  if (s < 32) {
    // SPLIT epilogue: write unnormalized fp32 O + (m,l) partials for top-half rows
    #pragma unroll
    for (int st = 0; st < 2; ++st) {
      const int plane = (c*2 + st)*16 + h;
      #pragma unroll
      for (int dn = 0; dn < 4; ++dn)
        #pragma unroll
        for (int i = 0; i < 4; ++i) {
          int rp = qb*64 + w*16 + fg + i - 1024;     // qb>=16 -> rp in [0,1024)
          Opart[((size_t)plane*1024 + rp)*64 + dn*16 + fr] = o_[st][dn][i];
        }
      if (lane < 16) {
        int rp = qb*64 + w*16 + fr - 1024;
        Ml[(size_t)plane*1024 + rp]         = m_[st];
        Ml[65536 + (size_t)plane*1024 + rp] = l_[st];
      }
    }
    return;
  }

  // UNSPLIT epilogue: differential combine + Yf write + LN partial sums
  const float lam = *lamp;
  float inv0 = __builtin_amdgcn_rcpf(l_[0]);
  float inv1 = __builtin_amdgcn_rcpf(l_[1]);
  float i0[4], i1[4];
  #pragma unroll
  for (int i = 0; i < 4; ++i) {
    i0[i] = __shfl(inv0, fg + i);
    i1[i] = __shfl(inv1, fg + i);
  }
  float sc1 = 0.f, sc2 = 0.f;
  #pragma unroll
  for (int dn = 0; dn < 4; ++dn)
    #pragma unroll
    for (int i = 0; i < 4; ++i) {
      int row = qb*64 + w*16 + fg + i;
      int col = h*64 + dn*16 + fr;
      float v = o_[0][dn][i] * i0[i] - lam * o_[1][dn][i] * i1[i];
      Yf[(size_t)row * DIM + col] = v;
      sc1 += v; sc2 += v * v;
    }
  #pragma unroll
  for (int off = 1; off <= 32; off <<= 1) {
    sc1 += __shfl_xor(sc1, off);
    sc2 += __shfl_xor(sc2, off);
  }
  if (lane == 0) { sb[w] = sc1; sb[4 + w] = sc2; }
  __syncthreads();
  if (tid == 0) {
    part[qb*16 + h]       = sb[0] + sb[1] + sb[2] + sb[3];
    part[512 + qb*16 + h] = sb[4] + sb[5] + sb[6] + sb[7];
  }
}

// ---------------- merge split chunks (top-half rows) + combine + LN partials -------
__global__ __launch_bounds__(256) void merge_stats(const float* __restrict__ Opart,
                                                   const float* __restrict__ Ml,
                                                   const float* __restrict__ lamp,
                                                   float* __restrict__ Yf,
                                                   float* __restrict__ part) {
  const int h = blockIdx.x & 15, sl = blockIdx.x >> 4;   // 16 slices x 64 rows
  const float lam = *lamp;
  float s = 0.f, s2 = 0.f;
  for (int e = threadIdx.x; e < 1024; e += 256) {   // 64 rows x 16 float4
    int rp = sl * 64 + (e >> 4);                    // 0..1023
    int d4 = (e & 15) * 4;
    float o[2][4];
    #pragma unroll
    for (int st = 0; st < 2; ++st) {
      int p0 = st*16 + h;            // chunk 0
      int p1 = (2 + st)*16 + h;      // chunk 1
      float m0 = Ml[(size_t)p0*1024 + rp], l0 = Ml[65536 + (size_t)p0*1024 + rp];
      float m1 = Ml[(size_t)p1*1024 + rp], l1 = Ml[65536 + (size_t)p1*1024 + rp];
      float M  = fmaxf(m0, m1);
      float w0 = __builtin_amdgcn_exp2f(m0 - M);
      float w1 = __builtin_amdgcn_exp2f(m1 - M);
      float inv = 1.f / (l0 * w0 + l1 * w1);
      float4 a = *(const float4*)(Opart + ((size_t)p0*1024 + rp)*64 + d4);
      float4 b = *(const float4*)(Opart + ((size_t)p1*1024 + rp)*64 + d4);
      o[st][0] = (a.x * w0 + b.x * w1) * inv;
      o[st][1] = (a.y * w0 + b.y * w1) * inv;
      o[st][2] = (a.z * w0 + b.z * w1) * inv;
      o[st][3] = (a.w * w0 + b.w * w1) * inv;
    }
    float4 v;
    v.x = o[0][0] - lam * o[1][0];
    v.y = o[0][1] - lam * o[1][1];
    v.z = o[0][2] - lam * o[1][2];
    v.w = o[0][3] - lam * o[1][3];
    s  += v.x + v.y + v.z + v.w;
    s2 += v.x*v.x + v.y*v.y + v.z*v.z + v.w*v.w;
    *(float4*)(Yf + (size_t)(1024 + rp) * DIM + h * 64 + d4) = v;
  }
  #pragma unroll
  for (int off = 32; off >= 1; off >>= 1) { s += __shfl_down(s, off); s2 += __shfl_down(s2, off); }
  __shared__ float sb[8];
  int wv = threadIdx.x >> 6, lane = threadIdx.x & 63;
  if (lane == 0) { sb[wv] = s; sb[4 + wv] = s2; }
  __syncthreads();
  if (threadIdx.x == 0) {
    part[256 + blockIdx.x]       = sb[0] + sb[1] + sb[2] + sb[3];
    part[512 + 256 + blockIdx.x] = sb[4] + sb[5] + sb[6] + sb[7];
  }
}

// ---------------- finalize per-head stats ----------------
__global__ void stats_final(const float* __restrict__ part, float* __restrict__ stat) {
  int hh = threadIdx.x;
  if (hh < 16) {
    float S = 0.f, S2 = 0.f;
    #pragma unroll
    for (int j = 0; j < 16; ++j) {
      S  += part[j*16 + hh] + part[256 + j*16 + hh];
      S2 += part[512 + j*16 + hh] + part[512 + 256 + j*16 + hh];
    }
    const float N = (float)(T_SEQ * HDIM);
    float mean = S / N;
    float var  = S2 / N - mean * mean;
    stat[hh]      = mean;
    stat[16 + hh] = rsqrtf(var + 1e-5f);
  }
}

__global__ void norm_cvt(const float* __restrict__ Y, const float* __restrict__ stats,
                         ushort* __restrict__ Yb) {
  int idx = (blockIdx.x * 256 + threadIdx.x) * 4;   // < T*DIM
  int col = idx & (DIM - 1);
  int h = col >> 6;
  float mean = stats[h], isd = stats[16 + h] * ONE_MINUS_LI;
  float4 v = *(const float4*)(Y + idx);
  ushort4 o4;
  o4.x = f2bf((v.x - mean) * isd);
  o4.y = f2bf((v.y - mean) * isd);
  o4.z = f2bf((v.z - mean) * isd);
  o4.w = f2bf((v.w - mean) * isd);
  *(ushort4*)(Yb + idx) = o4;
}

// ---------------- launch ----------------
extern "C" void kernel_launch(void* const* d_in, const int* in_sizes, int n_in,
                              void* d_out, int out_size, void* d_ws, size_t ws_size,
                              hipStream_t stream) {
  const float* x   = (const float*)d_in[0];
  const float* fc  = (const float*)d_in[1];
  const float* fs  = (const float*)d_in[2];
  const float* wq  = (const float*)d_in[3];
  const float* wk  = (const float*)d_in[4];
  const float* wv  = (const float*)d_in[5];
  const float* wo  = (const float*)d_in[6];
  const float* lq1 = (const float*)d_in[7];
  const float* lk1 = (const float*)d_in[8];
  const float* lq2 = (const float*)d_in[9];
  const float* lk2 = (const float*)d_in[10];
  float* out = (float*)d_out;

  char* ws = (char*)d_ws;
  // Liveness:
  //  phase1 (cvt/gemm1/reorg): Wob | xb | Wb | QKVb | Qr Kr Vt
  //  phase2 (attn):   Wob | Opart+Ml+Yf (over dead xb/Wb/QKVb) | Qr Kr Vt
  //  phase3 (merge..gemm2): Wob | Opart Ml Yf | Yb
  const size_t OFF_WOB  = 0;                 // 2 MB, live till end
  const size_t OFF_XB   = 2097152;           // 4 MB, dead after gemm1
  const size_t OFF_WB   = 6291456;           // 7 MB, dead after gemm1
  const size_t OFF_QKV  = 13631488;          // 14.68 MB, dead after reorg
  const size_t OFF_QR   = 28311552;          // 8 MB, live through attn
  const size_t OFF_KR   = 36700160;          // 4 MB, live through attn
  const size_t OFF_VT   = 40894464;          // 2 MB, live through attn
  const size_t OFF_OP   = 2097152;           // 16.78 MB fp32 O partials
  const size_t OFF_ML   = 18874368;          // 512 KB fp32 m+l
  const size_t OFF_Y    = 19398656;          // 8 MB fp32 Y  [ends 27787264 < OFF_QR]
  const size_t OFF_YB   = 42991616;          // 4 MB
  const size_t OFF_ST   = 47185920;          // stats + lam + partials

  ushort* xb   = (ushort*)(ws + OFF_XB);
  ushort* Wb   = (ushort*)(ws + OFF_WB);
  ushort* Wob  = (ushort*)(ws + OFF_WOB);
  ushort* QKVb = (ushort*)(ws + OFF_QKV);
  ushort* Qr   = (ushort*)(ws + OFF_QR);
  ushort* Kr   = (ushort*)(ws + OFF_KR);
  ushort* Vt   = (ushort*)(ws + OFF_VT);
  float*  Opart= (float*)(ws + OFF_OP);
  float*  Ml   = (float*)(ws + OFF_ML);
  float*  Yf   = (float*)(ws + OFF_Y);
  ushort* Yb   = (ushort*)(ws + OFF_YB);
  float*  stat = (float*)(ws + OFF_ST);
  float*  lamp = stat + 32;
  float*  part = stat + 64;                  // 1024 floats

  cvt_all<<<6656, 256, 0, stream>>>(x, wq, wk, wv, wo, xb, Wb, Wob);
  lam_kernel<<<1, 64, 0, stream>>>(lq1, lk1, lq2, lk2, lamp);

  gemm_bt<1><<<dim3(QKVN/128, T_SEQ/128), 256, 0, stream>>>(xb, Wb, QKVb, T_SEQ, QKVN, DIM);

  reorg<<<3584, 256, 0, stream>>>(QKVb, Qr, Kr, Vt, fc, fs);

  attn_kernel<<<768, 256, 0, stream>>>(Qr, Kr, Vt, lamp, Yf, part, Opart, Ml);

  merge_stats<<<256, 256, 0, stream>>>(Opart, Ml, lamp, Yf, part);
  stats_final<<<1, 64, 0, stream>>>(part, stat);
  norm_cvt<<<2048, 256, 0, stream>>>(Yf, stat, Yb);

  gemm_bt<0><<<dim3(DIM/128, T_SEQ/128), 256, 0, stream>>>(Yb, Wob, out, T_SEQ, DIM, DIM);
}

// Round 9
// 169.239 us; speedup vs baseline: 2.4681x; 1.4139x over previous
//
#include <hip/hip_runtime.h>
#include <hip/hip_bf16.h>
#include <cstdint>

#define T_SEQ 2048
#define DIM   1024
#define NHEAD 16
#define NKVH  8
#define HDIM  64
#define QKVN  3584   // 2048 (q) + 1024 (k) + 512 (v)

static constexpr float LAMBDA_INIT_F = 0.3555090675909693f;
static constexpr float ONE_MINUS_LI  = 0.6444909324090307f;
static constexpr float QSCALE_EXP2   = 0.1803368801111144f;  // 0.125 * log2(e)

typedef __bf16 bf16x8 __attribute__((ext_vector_type(8)));
typedef float  f32x4  __attribute__((ext_vector_type(4)));

static __device__ __forceinline__ ushort f2bf(float f) {
  union { float f; uint32_t u; } x; x.f = f;
  uint32_t u = x.u;
  uint32_t r = (u + 0x7fffu + ((u >> 16) & 1u)) >> 16;
  return (ushort)r;
}
static __device__ __forceinline__ float bf2f(ushort u) {
  union { uint32_t u; float f; } x; x.u = ((uint32_t)u) << 16; return x.f;
}
static __device__ __forceinline__ f32x4 zero4() {
  f32x4 z = {0.f, 0.f, 0.f, 0.f}; return z;
}
// Fragment-interleaved layout: within each 32-element k-block, quad q (=k>>2) is
// stored at offset ((q&3)<<3) + ((q>>2)<<2). A lane's 8 frag elements
// {4g..4g+3, 16+4g..19+4g} land contiguously at [8g..8g+7] -> one b128 load.
static __device__ __forceinline__ bf16x8 ldfrag128(const ushort* p) {
  union { bf16x8 v; uint4 u; } r;
  r.u = *(const uint4*)p;
  return r.v;
}
// async global->LDS, 16B per lane; lds dest = base + lane*16 (wave-uniform base)
static __device__ __forceinline__ void gll16(const ushort* g, ushort* l) {
  __builtin_amdgcn_global_load_lds(
      (const __attribute__((address_space(1))) uint32_t*)g,
      (__attribute__((address_space(3))) uint32_t*)l, 16, 0, 0);
}

// ---------------- fused fp32->bf16 conversion, frag-interleaved output -------------
__global__ void cvt_all(const float* __restrict__ x,  const float* __restrict__ wq,
                        const float* __restrict__ wk, const float* __restrict__ wv,
                        const float* __restrict__ wo,
                        ushort* __restrict__ xb, ushort* __restrict__ Wb,
                        ushort* __restrict__ Wob) {
  int g = (blockIdx.x * 256 + threadIdx.x) * 4;   // < 6815744, 4-aligned
  float4 v; ushort* dst; int j;
  if (g < 2097152) {
    v = *(const float4*)(x + g); dst = xb; j = g;
  } else if (g < 5767168) {
    j = g - 2097152;
    const float* src = (j < 2097152) ? (wq + j)
                     : (j < 3145728) ? (wk + (j - 2097152))
                                     : (wv + (j - 3145728));
    v = *(const float4*)src; dst = Wb;
  } else {
    j = g - 5767168;
    v = *(const float4*)(wo + j); dst = Wob;
  }
  int q = (j & 31) >> 2;                         // quad within 32-block
  int jp = (j & ~31) + ((q & 3) << 3) + ((q >> 2) << 2);
  ushort4 o4;
  o4.x = f2bf(v.x); o4.y = f2bf(v.y); o4.z = f2bf(v.z); o4.w = f2bf(v.w);
  *(ushort4*)(dst + jp) = o4;
}

__global__ void lam_kernel(const float* __restrict__ lq1, const float* __restrict__ lk1,
                           const float* __restrict__ lq2, const float* __restrict__ lk2,
                           float* __restrict__ lam) {
  int lane = threadIdx.x;  // 64 threads
  float p1 = lq1[lane] * lk1[lane];
  float p2 = lq2[lane] * lk2[lane];
  #pragma unroll
  for (int off = 32; off >= 1; off >>= 1) {
    p1 += __shfl_down(p1, off);
    p2 += __shfl_down(p2, off);
  }
  if (lane == 0) *lam = expf(p1) - expf(p2) + LAMBDA_INIT_F;
}

// ---------------- GEMM (m97 + T1 swizzle), frag-interleaved inputs, b128 reads -----
template<int BF16OUT>
__global__ __launch_bounds__(256) void gemm_bt(const ushort* __restrict__ A,
                                               const ushort* __restrict__ W,
                                               void* __restrict__ Cout,
                                               int M, int N, int K) {
  __shared__ __align__(16) ushort As[128 * 32];
  __shared__ __align__(16) ushort Ws[128 * 32];
  const int tid  = threadIdx.x;
  const int lane = tid & 63;
  const int w    = tid >> 6;
  const int wr   = w >> 1, wc = w & 1;
  const int nwg = gridDim.x * gridDim.y;
  int id  = blockIdx.x * gridDim.y + blockIdx.y;
  int sw  = (id & 7) * (nwg >> 3) + (id >> 3);
  const int bm = (sw % gridDim.y) * 128;
  const int bn = (sw / gridDim.y) * 128;
  const int fr = lane & 15;
  const int fg = (lane >> 4) * 4;
  const int g8 = (lane >> 4) * 8;

  f32x4 acc[4][4];
  #pragma unroll
  for (int m = 0; m < 4; ++m)
    #pragma unroll
    for (int n = 0; n < 4; ++n) acc[m][n] = zero4();

  const int col  = (lane & 3) * 8;
  const int row0 = w * 16 + (lane >> 2);
  const int row1 = row0 + 64;
  const ushort* ga0 = A + (size_t)(bm + row0) * K + col;
  const ushort* ga1 = A + (size_t)(bm + row1) * K + col;
  const ushort* gw0 = W + (size_t)(bn + row0) * K + col;
  const ushort* gw1 = W + (size_t)(bn + row1) * K + col;
  ushort* la0 = As + (w * 512);
  ushort* la1 = As + (w * 512) + 2048;
  ushort* lw0 = Ws + (w * 512);
  ushort* lw1 = Ws + (w * 512) + 2048;

  for (int k0 = 0; k0 < K; k0 += 32) {
    gll16(ga0 + k0, la0);
    gll16(ga1 + k0, la1);
    gll16(gw0 + k0, lw0);
    gll16(gw1 + k0, lw1);
    __syncthreads();
    bf16x8 af[4], bfr[4];
    #pragma unroll
    for (int m = 0; m < 4; ++m) af[m]  = ldfrag128(&As[(wr*64 + m*16 + fr) * 32 + g8]);
    #pragma unroll
    for (int n = 0; n < 4; ++n) bfr[n] = ldfrag128(&Ws[(wc*64 + n*16 + fr) * 32 + g8]);
    #pragma unroll
    for (int m = 0; m < 4; ++m)
      #pragma unroll
      for (int n = 0; n < 4; ++n)
        acc[m][n] = __builtin_amdgcn_mfma_f32_16x16x32_bf16(af[m], bfr[n], acc[m][n], 0, 0, 0);
    __syncthreads();
  }

  #pragma unroll
  for (int m = 0; m < 4; ++m)
    #pragma unroll
    for (int n = 0; n < 4; ++n)
      #pragma unroll
      for (int i = 0; i < 4; ++i) {
        int row = bm + wr*64 + m*16 + fg + i;
        int colg = bn + wc*64 + n*16 + fr;
        float v = acc[m][n][i];
        if (BF16OUT) ((ushort*)Cout)[(size_t)row * N + colg] = f2bf(v);
        else         ((float*)Cout)[(size_t)row * N + colg]  = v;
      }
}

// ---------------- fused RoPE Q, RoPE K, pack V -> frag-interleaved layouts ---------
// Q scaled by 0.125*log2(e). Qr/Kr: d-dim permuted per 32-block; Vt: t-dim permuted.
__global__ void reorg(const ushort* __restrict__ QKV, ushort* __restrict__ Qr,
                      ushort* __restrict__ Kr, ushort* __restrict__ Vt,
                      const float* __restrict__ fc, const float* __restrict__ fs) {
  int idx = blockIdx.x * 256 + threadIdx.x;   // < 917504
  if (idx < 786432) {
    // RoPE, 4 interleaved pairs = 8 consecutive logical d per thread
    int nheads, col_off; ushort* dst; float scale; int id;
    if (idx < 524288) { id = idx * 4; nheads = NHEAD; col_off = 0; dst = Qr; scale = QSCALE_EXP2; }
    else { id = (idx - 524288) * 4; nheads = NKVH; col_off = 2048; dst = Kr; scale = 1.0f; }
    int per_t = nheads * 64;
    int t  = id / per_t;
    int r  = id - t * per_t;
    int hh = r >> 6;
    int c2 = (r >> 5) & 1;
    int j  = r & 31;                      // multiple of 4; logical d0 = 2j
    int cl = col_off + hh * 128 + c2 * 64 + 2 * j;
    uint4 raw = *(const uint4*)(QKV + (size_t)t * QKVN + cl);
    const ushort* rp = (const ushort*)&raw;
    float c4[4], s4[4];
    *(float4*)c4 = *(const float4*)(fc + t * 32 + j);
    *(float4*)s4 = *(const float4*)(fs + t * 32 + j);
    ushort outv[8];
    #pragma unroll
    for (int p = 0; p < 4; ++p) {
      float rv = bf2f(rp[2*p]), iv = bf2f(rp[2*p + 1]);
      outv[2*p]     = f2bf((rv * c4[p] - iv * s4[p]) * scale);
      outv[2*p + 1] = f2bf((rv * s4[p] + iv * c4[p]) * scale);
    }
    int d0 = 2 * j;
    int o  = d0 & 31;                     // 0,8,16,24
    int q0 = o >> 2;                      // 0,2,4,6
    int s0 = ((q0 & 3) << 3) + ((q0 >> 2) << 2);
    int s1 = (((q0+1) & 3) << 3) + (((q0+1) >> 2) << 2);
    size_t ob = ((size_t)(c2 * nheads + hh) * T_SEQ + t) * HDIM + (d0 & ~31);
    *(uint2*)(dst + ob + s0) = *(const uint2*)(outv);
    *(uint2*)(dst + ob + s1) = *(const uint2*)(outv + 4);
  } else {
    // V transpose: 8 t-consecutive elems, t-permuted within 32-blocks
    int id = (idx - 786432) * 8;           // < 1048576
    int t = id & (T_SEQ - 1);              // multiple of 8
    int rest = id >> 11;                   // kh*64 + d
    ushort outv[8];
    #pragma unroll
    for (int p = 0; p < 8; ++p) outv[p] = QKV[(size_t)(t + p) * QKVN + 3072 + rest];
    int o  = t & 31;
    int q0 = o >> 2;
    int s0 = ((q0 & 3) << 3) + ((q0 >> 2) << 2);
    int s1 = (((q0+1) & 3) << 3) + (((q0+1) >> 2) << 2);
    size_t ob = (size_t)rest * T_SEQ + (t & ~31);
    *(uint2*)(Vt + ob + s0) = *(const uint2*)(outv);
    *(uint2*)(Vt + ob + s1) = *(const uint2*)(outv + 4);
  }
}

// ---------------- flash attention: stream-per-wave, b128 frags, in-block combine ---
// 512 blocks = (head, qb). Wave w: stream st = w>>1, q-half qh = w&1 (32 q-rows as
// two 16-q chunks). K A-frags are q-independent -> read once per (n,ks), reused for
// both chunks (halves K LDS reads). Epilogue: stream-1 waves park O2 in dead Ks LDS;
// stream-0 waves combine, write Yf, accumulate LN partials.
__global__ __launch_bounds__(256) void attn_kernel(const ushort* __restrict__ Qr,
                                                   const ushort* __restrict__ Kr,
                                                   const ushort* __restrict__ Vt,
                                                   const float* __restrict__ lamp,
                                                   float* __restrict__ Yf,
                                                   float* __restrict__ part) {
  const int bx = blockIdx.x;          // 0..511
  const int h  = bx & 15;
  const int jb = bx >> 4;             // pair (jb, jb+16) sums to 32 tiles
  const int qb = (jb < 16) ? (31 - jb) : (jb - 16);
  const int kh = h >> 1;
  const int tid = threadIdx.x;
  const int lane = tid & 63;
  const int w   = tid >> 6;
  const int st  = w >> 1;             // stream 0/1
  const int qh  = w & 1;              // q-half 0/1
  const int fr  = lane & 15;
  const int fg  = (lane >> 4) * 4;
  const int g8  = (lane >> 4) * 8;

  __shared__ __align__(16) ushort Ks[2][64][72];
  __shared__ __align__(16) ushort Vs[64][72];
  __shared__ float sb[8];

  // Q fragments for this wave's stream, two 16-q chunks (frag-interleaved global)
  bf16x8 qf[2][2];                     // [qs][ks]
  #pragma unroll
  for (int qs = 0; qs < 2; ++qs) {
    const int row = qb * 64 + qh * 32 + qs * 16 + fr;
    const ushort* qp = Qr + ((size_t)(st * NHEAD + h) * T_SEQ + row) * HDIM;
    qf[qs][0] = ldfrag128(qp + g8);
    qf[qs][1] = ldfrag128(qp + 32 + g8);
  }

  float m_[2] = {-__builtin_inff(), -__builtin_inff()};
  float l_[2] = {0.f, 0.f};
  f32x4 o_[2][4];
  #pragma unroll
  for (int qs = 0; qs < 2; ++qs)
    #pragma unroll
    for (int dn = 0; dn < 4; ++dn) o_[qs][dn] = zero4();

  // K1/K2/V staging (block-wide, raw copy of permuted global)
  const int srow = tid >> 2, scol = (tid & 3) * 16;
  uint4 kpre[2][2], vpre[2];
  {
    #pragma unroll
    for (int c2 = 0; c2 < 2; ++c2) {
      const ushort* src = Kr + ((size_t)(c2 * NKVH + kh) * T_SEQ + srow) * HDIM + scol;
      kpre[c2][0] = *(const uint4*)src;
      kpre[c2][1] = *(const uint4*)(src + 8);
    }
    const ushort* vsrc = Vt + (size_t)(kh * 64 + srow) * T_SEQ + scol;
    vpre[0] = *(const uint4*)vsrc;
    vpre[1] = *(const uint4*)(vsrc + 8);
  }

  for (int kt = 0; kt <= qb; ++kt) {
    __syncthreads();                 // prev iteration's LDS reads complete
    #pragma unroll
    for (int c2 = 0; c2 < 2; ++c2) {
      *(uint4*)&Ks[c2][srow][scol]     = kpre[c2][0];
      *(uint4*)&Ks[c2][srow][scol + 8] = kpre[c2][1];
    }
    *(uint4*)&Vs[srow][scol]     = vpre[0];
    *(uint4*)&Vs[srow][scol + 8] = vpre[1];
    if (kt < qb) {
      const int nb = (kt + 1) * 64;
      #pragma unroll
      for (int c2 = 0; c2 < 2; ++c2) {
        const ushort* src = Kr + ((size_t)(c2 * NKVH + kh) * T_SEQ + nb + srow) * HDIM + scol;
        kpre[c2][0] = *(const uint4*)src;
        kpre[c2][1] = *(const uint4*)(src + 8);
      }
      const ushort* vsrc = Vt + (size_t)(kh * 64 + srow) * T_SEQ + nb + scol;
      vpre[0] = *(const uint4*)vsrc;
      vpre[1] = *(const uint4*)(vsrc + 8);
    }
    __syncthreads();                 // staging visible

    // S^T: mfma(K rows, Q cols); one K frag serves both q-chunks
    float sv[2][4][4];
    #pragma unroll
    for (int n = 0; n < 4; ++n) {
      f32x4 a0 = zero4(), a1 = zero4();
      #pragma unroll
      for (int ks = 0; ks < 2; ++ks) {
        bf16x8 ak = ldfrag128(&Ks[st][n*16 + fr][ks*32 + g8]);
        a0 = __builtin_amdgcn_mfma_f32_16x16x32_bf16(ak, qf[0][ks], a0, 0, 0, 0);
        a1 = __builtin_amdgcn_mfma_f32_16x16x32_bf16(ak, qf[1][ks], a1, 0, 0, 0);
      }
      #pragma unroll
      for (int i = 0; i < 4; ++i) { sv[0][n][i] = a0[i]; sv[1][n][i] = a1[i]; }
    }
    if (kt == qb) {                  // causal mask on diagonal tile
      #pragma unroll
      for (int qs = 0; qs < 2; ++qs) {
        const int qloc = qh*32 + qs*16 + fr;
        #pragma unroll
        for (int n = 0; n < 4; ++n)
          #pragma unroll
          for (int i = 0; i < 4; ++i)
            if (n*16 + fg + i > qloc) sv[qs][n][i] = -__builtin_inff();
      }
    }

    bf16x8 pa[2][2];
    #pragma unroll
    for (int qs = 0; qs < 2; ++qs) {
      float rm = -__builtin_inff();
      #pragma unroll
      for (int n = 0; n < 4; ++n)
        #pragma unroll
        for (int i = 0; i < 4; ++i) rm = fmaxf(rm, sv[qs][n][i]);
      rm = fmaxf(rm, __shfl_xor(rm, 16));
      rm = fmaxf(rm, __shfl_xor(rm, 32));
      if (!__all(rm <= m_[qs] + 8.f)) {   // defer-max (exp2 domain, THR=8)
        float mnew = fmaxf(m_[qs], rm);
        float sc = __builtin_amdgcn_exp2f(m_[qs] - mnew);
        m_[qs] = mnew;
        l_[qs] *= sc;
        float scs[4];
        #pragma unroll
        for (int i = 0; i < 4; ++i) scs[i] = __shfl(sc, fg + i);
        #pragma unroll
        for (int dn = 0; dn < 4; ++dn)
          #pragma unroll
          for (int i = 0; i < 4; ++i) o_[qs][dn][i] *= scs[i];
      }
      float rs = 0.f;
      #pragma unroll
      for (int n = 0; n < 4; ++n)
        #pragma unroll
        for (int i = 0; i < 4; ++i) {
          float p = __builtin_amdgcn_exp2f(sv[qs][n][i] - m_[qs]);
          sv[qs][n][i] = p; rs += p;
        }
      rs += __shfl_xor(rs, 16);
      rs += __shfl_xor(rs, 32);
      l_[qs] += rs;
      #pragma unroll
      for (int ks = 0; ks < 2; ++ks)
        #pragma unroll
        for (int n2 = 0; n2 < 2; ++n2)
          #pragma unroll
          for (int i = 0; i < 4; ++i)
            pa[qs][ks][n2*4 + i] = (__bf16)sv[qs][2*ks + n2][i];
    }

    // O += P @ V; one V frag serves both q-chunks
    #pragma unroll
    for (int ks = 0; ks < 2; ++ks)
      #pragma unroll
      for (int dn = 0; dn < 4; ++dn) {
        bf16x8 bv = ldfrag128(&Vs[dn*16 + fr][ks*32 + g8]);
        o_[0][dn] = __builtin_amdgcn_mfma_f32_16x16x32_bf16(pa[0][ks], bv, o_[0][dn], 0, 0, 0);
        o_[1][dn] = __builtin_amdgcn_mfma_f32_16x16x32_bf16(pa[1][ks], bv, o_[1][dn], 0, 0, 0);
      }
  }

  // epilogue: normalize; exchange stream-1 O via LDS; combine + Yf + LN partials
  float iq[2][4];
  #pragma unroll
  for (int qs = 0; qs < 2; ++qs) {
    float inv = __builtin_amdgcn_rcpf(l_[qs]);
    #pragma unroll
    for (int i = 0; i < 4; ++i) iq[qs][i] = __shfl(inv, fg + i);
  }
  float* ob = (float*)&Ks[0][0][0];   // 16 KB over dead K buffers
  __syncthreads();
  if (st == 1) {
    #pragma unroll
    for (int qs = 0; qs < 2; ++qs)
      #pragma unroll
      for (int dn = 0; dn < 4; ++dn)
        #pragma unroll
        for (int i = 0; i < 4; ++i)
          ob[(qh*32 + qs*16 + fg + i)*64 + dn*16 + fr] = o_[qs][dn][i] * iq[qs][i];
  }
  __syncthreads();
  if (st == 0) {
    const float lam = *lamp;
    float s = 0.f, s2 = 0.f;
    #pragma unroll
    for (int qs = 0; qs < 2; ++qs)
      #pragma unroll
      for (int dn = 0; dn < 4; ++dn)
        #pragma unroll
        for (int i = 0; i < 4; ++i) {
          int r64 = qh*32 + qs*16 + fg + i;
          int d   = dn*16 + fr;
          float v = o_[qs][dn][i] * iq[qs][i] - lam * ob[r64*64 + d];
          Yf[(size_t)(qb*64 + r64) * DIM + h*64 + d] = v;
          s += v; s2 += v * v;
        }
    #pragma unroll
    for (int off = 1; off <= 32; off <<= 1) {
      s  += __shfl_xor(s, off);
      s2 += __shfl_xor(s2, off);
    }
    if (lane == 0) { sb[w] = s; sb[4 + w] = s2; }   // w in {0,1}
  }
  __syncthreads();
  if (tid == 0) {
    part[bx]       = sb[0] + sb[1];
    part[512 + bx] = sb[4] + sb[5];
  }
}

// ---------------- finalize per-head stats ----------------
__global__ void stats_final(const float* __restrict__ part, float* __restrict__ stat) {
  int hh = threadIdx.x;
  if (hh < 16) {
    float S = 0.f, S2 = 0.f;
    #pragma unroll
    for (int j = 0; j < 32; ++j) { S += part[j*16 + hh]; S2 += part[512 + j*16 + hh]; }
    const float N = (float)(T_SEQ * HDIM);
    float mean = S / N;
    float var  = S2 / N - mean * mean;
    stat[hh]      = mean;
    stat[16 + hh] = rsqrtf(var + 1e-5f);
  }
}

// Yb written frag-interleaved (gemm2 expects it)
__global__ void norm_cvt(const float* __restrict__ Y, const float* __restrict__ stats,
                         ushort* __restrict__ Yb) {
  int idx = (blockIdx.x * 256 + threadIdx.x) * 4;   // < T*DIM, 4-aligned
  int col = idx & (DIM - 1);
  int h = col >> 6;
  float mean = stats[h], isd = stats[16 + h] * ONE_MINUS_LI;
  float4 v = *(const float4*)(Y + idx);
  ushort4 o4;
  o4.x = f2bf((v.x - mean) * isd);
  o4.y = f2bf((v.y - mean) * isd);
  o4.z = f2bf((v.z - mean) * isd);
  o4.w = f2bf((v.w - mean) * isd);
  int q = (col & 31) >> 2;
  int idxp = (idx & ~31) + ((q & 3) << 3) + ((q >> 2) << 2);
  *(ushort4*)(Yb + idxp) = o4;
}

// ---------------- launch ----------------
extern "C" void kernel_launch(void* const* d_in, const int* in_sizes, int n_in,
                              void* d_out, int out_size, void* d_ws, size_t ws_size,
                              hipStream_t stream) {
  const float* x   = (const float*)d_in[0];
  const float* fc  = (const float*)d_in[1];
  const float* fs  = (const float*)d_in[2];
  const float* wq  = (const float*)d_in[3];
  const float* wk  = (const float*)d_in[4];
  const float* wv  = (const float*)d_in[5];
  const float* wo  = (const float*)d_in[6];
  const float* lq1 = (const float*)d_in[7];
  const float* lk1 = (const float*)d_in[8];
  const float* lq2 = (const float*)d_in[9];
  const float* lk2 = (const float*)d_in[10];
  float* out = (float*)d_out;

  char* ws = (char*)d_ws;
  const size_t OFF_WOB  = 0;                 // 2 MB, live till end
  const size_t OFF_XB   = 2097152;           // 4 MB, dead after gemm1
  const size_t OFF_WB   = 6291456;           // 7 MB, dead after gemm1
  const size_t OFF_QKV  = 13631488;          // 14.68 MB, dead after reorg
  const size_t OFF_QR   = 28311552;          // 8 MB
  const size_t OFF_KR   = 36700160;          // 4 MB
  const size_t OFF_VT   = 40894464;          // 2 MB
  const size_t OFF_Y    = 18874368;          // 8 MB over dead QKV tail
  const size_t OFF_YB   = 42991616;          // 4 MB
  const size_t OFF_ST   = 47185920;          // stats + lam + partials

  ushort* xb   = (ushort*)(ws + OFF_XB);
  ushort* Wb   = (ushort*)(ws + OFF_WB);
  ushort* Wob  = (ushort*)(ws + OFF_WOB);
  ushort* QKVb = (ushort*)(ws + OFF_QKV);
  ushort* Qr   = (ushort*)(ws + OFF_QR);
  ushort* Kr   = (ushort*)(ws + OFF_KR);
  ushort* Vt   = (ushort*)(ws + OFF_VT);
  float*  Yf   = (float*)(ws + OFF_Y);
  ushort* Yb   = (ushort*)(ws + OFF_YB);
  float*  stat = (float*)(ws + OFF_ST);
  float*  lamp = stat + 32;
  float*  part = stat + 64;                  // 1024 floats

  cvt_all<<<6656, 256, 0, stream>>>(x, wq, wk, wv, wo, xb, Wb, Wob);
  lam_kernel<<<1, 64, 0, stream>>>(lq1, lk1, lq2, lk2, lamp);

  gemm_bt<1><<<dim3(QKVN/128, T_SEQ/128), 256, 0, stream>>>(xb, Wb, QKVb, T_SEQ, QKVN, DIM);

  reorg<<<3584, 256, 0, stream>>>(QKVb, Qr, Kr, Vt, fc, fs);

  attn_kernel<<<512, 256, 0, stream>>>(Qr, Kr, Vt, lamp, Yf, part);

  stats_final<<<1, 64, 0, stream>>>(part, stat);
  norm_cvt<<<2048, 256, 0, stream>>>(Yf, stat, Yb);

  gemm_bt<0><<<dim3(DIM/128, T_SEQ/128), 256, 0, stream>>>(Yb, Wob, out, T_SEQ, DIM, DIM);
}

// Round 10
// 147.323 us; speedup vs baseline: 2.8353x; 1.1488x over previous
//
#include <hip/hip_runtime.h>
#include <hip/hip_bf16.h>
#include <cstdint>

#define T_SEQ 2048
#define DIM   1024
#define NHEAD 16
#define NKVH  8
#define HDIM  64
#define QKVN  3584   // 2048 (q) + 1024 (k) + 512 (v)

static constexpr float LAMBDA_INIT_F = 0.3555090675909693f;
static constexpr float ONE_MINUS_LI  = 0.6444909324090307f;
static constexpr float QSCALE_EXP2   = 0.1803368801111144f;  // 0.125 * log2(e)

typedef __bf16 bf16x8 __attribute__((ext_vector_type(8)));
typedef float  f32x4  __attribute__((ext_vector_type(4)));

static __device__ __forceinline__ ushort f2bf(float f) {
  union { float f; uint32_t u; } x; x.f = f;
  uint32_t u = x.u;
  uint32_t r = (u + 0x7fffu + ((u >> 16) & 1u)) >> 16;
  return (ushort)r;
}
static __device__ __forceinline__ float bf2f(ushort u) {
  union { uint32_t u; float f; } x; x.u = ((uint32_t)u) << 16; return x.f;
}
static __device__ __forceinline__ f32x4 zero4() {
  f32x4 z = {0.f, 0.f, 0.f, 0.f}; return z;
}
// Fragment-interleaved layout: within each 32-element k-block, quad q (=k>>2) is
// stored at offset ((q&3)<<3) + ((q>>2)<<2). A lane's 8 frag elements
// {4g..4g+3, 16+4g..19+4g} land contiguously at [8g..8g+7] -> one 16B load.
static __device__ __forceinline__ bf16x8 ldfrag128(const ushort* p) {
  union { bf16x8 v; uint4 u; } r;
  r.u = *(const uint4*)p;
  return r.v;
}
// async global->LDS, 16B per lane; lds dest = base + lane*16 (wave-uniform base)
static __device__ __forceinline__ void gll16(const ushort* g, ushort* l) {
  __builtin_amdgcn_global_load_lds(
      (const __attribute__((address_space(1))) uint32_t*)g,
      (__attribute__((address_space(3))) uint32_t*)l, 16, 0, 0);
}

// ---------------- fused fp32->bf16 conversion, frag-interleaved output -------------
__global__ void cvt_all(const float* __restrict__ x,  const float* __restrict__ wq,
                        const float* __restrict__ wk, const float* __restrict__ wv,
                        const float* __restrict__ wo,
                        ushort* __restrict__ xb, ushort* __restrict__ Wb,
                        ushort* __restrict__ Wob) {
  int g = (blockIdx.x * 256 + threadIdx.x) * 4;   // < 6815744, 4-aligned
  float4 v; ushort* dst; int j;
  if (g < 2097152) {
    v = *(const float4*)(x + g); dst = xb; j = g;
  } else if (g < 5767168) {
    j = g - 2097152;
    const float* src = (j < 2097152) ? (wq + j)
                     : (j < 3145728) ? (wk + (j - 2097152))
                                     : (wv + (j - 3145728));
    v = *(const float4*)src; dst = Wb;
  } else {
    j = g - 5767168;
    v = *(const float4*)(wo + j); dst = Wob;
  }
  int q = (j & 31) >> 2;                         // quad within 32-block
  int jp = (j & ~31) + ((q & 3) << 3) + ((q >> 2) << 2);
  ushort4 o4;
  o4.x = f2bf(v.x); o4.y = f2bf(v.y); o4.z = f2bf(v.z); o4.w = f2bf(v.w);
  *(ushort4*)(dst + jp) = o4;
}

__global__ void lam_kernel(const float* __restrict__ lq1, const float* __restrict__ lk1,
                           const float* __restrict__ lq2, const float* __restrict__ lk2,
                           float* __restrict__ lam) {
  int lane = threadIdx.x;  // 64 threads
  float p1 = lq1[lane] * lk1[lane];
  float p2 = lq2[lane] * lk2[lane];
  #pragma unroll
  for (int off = 32; off >= 1; off >>= 1) {
    p1 += __shfl_down(p1, off);
    p2 += __shfl_down(p2, off);
  }
  if (lane == 0) *lam = expf(p1) - expf(p2) + LAMBDA_INIT_F;
}

// ---------------- GEMM (m97 + T1 swizzle), frag-interleaved inputs, b128 reads -----
template<int BF16OUT>
__global__ __launch_bounds__(256) void gemm_bt(const ushort* __restrict__ A,
                                               const ushort* __restrict__ W,
                                               void* __restrict__ Cout,
                                               int M, int N, int K) {
  __shared__ __align__(16) ushort As[128 * 32];
  __shared__ __align__(16) ushort Ws[128 * 32];
  const int tid  = threadIdx.x;
  const int lane = tid & 63;
  const int w    = tid >> 6;
  const int wr   = w >> 1, wc = w & 1;
  const int nwg = gridDim.x * gridDim.y;
  int id  = blockIdx.x * gridDim.y + blockIdx.y;
  int sw  = (id & 7) * (nwg >> 3) + (id >> 3);
  const int bm = (sw % gridDim.y) * 128;
  const int bn = (sw / gridDim.y) * 128;
  const int fr = lane & 15;
  const int fg = (lane >> 4) * 4;
  const int g8 = (lane >> 4) * 8;

  f32x4 acc[4][4];
  #pragma unroll
  for (int m = 0; m < 4; ++m)
    #pragma unroll
    for (int n = 0; n < 4; ++n) acc[m][n] = zero4();

  const int col  = (lane & 3) * 8;
  const int row0 = w * 16 + (lane >> 2);
  const int row1 = row0 + 64;
  const ushort* ga0 = A + (size_t)(bm + row0) * K + col;
  const ushort* ga1 = A + (size_t)(bm + row1) * K + col;
  const ushort* gw0 = W + (size_t)(bn + row0) * K + col;
  const ushort* gw1 = W + (size_t)(bn + row1) * K + col;
  ushort* la0 = As + (w * 512);
  ushort* la1 = As + (w * 512) + 2048;
  ushort* lw0 = Ws + (w * 512);
  ushort* lw1 = Ws + (w * 512) + 2048;

  for (int k0 = 0; k0 < K; k0 += 32) {
    gll16(ga0 + k0, la0);
    gll16(ga1 + k0, la1);
    gll16(gw0 + k0, lw0);
    gll16(gw1 + k0, lw1);
    __syncthreads();
    bf16x8 af[4], bfr[4];
    #pragma unroll
    for (int m = 0; m < 4; ++m) af[m]  = ldfrag128(&As[(wr*64 + m*16 + fr) * 32 + g8]);
    #pragma unroll
    for (int n = 0; n < 4; ++n) bfr[n] = ldfrag128(&Ws[(wc*64 + n*16 + fr) * 32 + g8]);
    #pragma unroll
    for (int m = 0; m < 4; ++m)
      #pragma unroll
      for (int n = 0; n < 4; ++n)
        acc[m][n] = __builtin_amdgcn_mfma_f32_16x16x32_bf16(af[m], bfr[n], acc[m][n], 0, 0, 0);
    __syncthreads();
  }

  #pragma unroll
  for (int m = 0; m < 4; ++m)
    #pragma unroll
    for (int n = 0; n < 4; ++n)
      #pragma unroll
      for (int i = 0; i < 4; ++i) {
        int row = bm + wr*64 + m*16 + fg + i;
        int colg = bn + wc*64 + n*16 + fr;
        float v = acc[m][n][i];
        if (BF16OUT) ((ushort*)Cout)[(size_t)row * N + colg] = f2bf(v);
        else         ((float*)Cout)[(size_t)row * N + colg]  = v;
      }
}

// ---------------- fused RoPE Q, RoPE K, pack V -> frag-interleaved layouts ---------
// Q scaled by 0.125*log2(e). Qr/Kr: d-dim permuted per 32-block; Vt: t-dim permuted.
__global__ void reorg(const ushort* __restrict__ QKV, ushort* __restrict__ Qr,
                      ushort* __restrict__ Kr, ushort* __restrict__ Vt,
                      const float* __restrict__ fc, const float* __restrict__ fs) {
  int idx = blockIdx.x * 256 + threadIdx.x;   // < 917504
  if (idx < 786432) {
    // RoPE, 4 interleaved pairs = 8 consecutive logical d per thread
    int nheads, col_off; ushort* dst; float scale; int id;
    if (idx < 524288) { id = idx * 4; nheads = NHEAD; col_off = 0; dst = Qr; scale = QSCALE_EXP2; }
    else { id = (idx - 524288) * 4; nheads = NKVH; col_off = 2048; dst = Kr; scale = 1.0f; }
    int per_t = nheads * 64;
    int t  = id / per_t;
    int r  = id - t * per_t;
    int hh = r >> 6;
    int c2 = (r >> 5) & 1;
    int j  = r & 31;                      // multiple of 4; logical d0 = 2j
    int cl = col_off + hh * 128 + c2 * 64 + 2 * j;
    uint4 raw = *(const uint4*)(QKV + (size_t)t * QKVN + cl);
    const ushort* rp = (const ushort*)&raw;
    float c4[4], s4[4];
    *(float4*)c4 = *(const float4*)(fc + t * 32 + j);
    *(float4*)s4 = *(const float4*)(fs + t * 32 + j);
    ushort outv[8];
    #pragma unroll
    for (int p = 0; p < 4; ++p) {
      float rv = bf2f(rp[2*p]), iv = bf2f(rp[2*p + 1]);
      outv[2*p]     = f2bf((rv * c4[p] - iv * s4[p]) * scale);
      outv[2*p + 1] = f2bf((rv * s4[p] + iv * c4[p]) * scale);
    }
    int d0 = 2 * j;
    int o  = d0 & 31;                     // 0,8,16,24
    int q0 = o >> 2;                      // 0,2,4,6
    int s0 = ((q0 & 3) << 3) + ((q0 >> 2) << 2);
    int s1 = (((q0+1) & 3) << 3) + (((q0+1) >> 2) << 2);
    size_t ob = ((size_t)(c2 * nheads + hh) * T_SEQ + t) * HDIM + (d0 & ~31);
    *(uint2*)(dst + ob + s0) = *(const uint2*)(outv);
    *(uint2*)(dst + ob + s1) = *(const uint2*)(outv + 4);
  } else {
    // V transpose: 8 t-consecutive elems, t-permuted within 32-blocks
    int id = (idx - 786432) * 8;           // < 1048576
    int t = id & (T_SEQ - 1);              // multiple of 8
    int rest = id >> 11;                   // kh*64 + d
    ushort outv[8];
    #pragma unroll
    for (int p = 0; p < 8; ++p) outv[p] = QKV[(size_t)(t + p) * QKVN + 3072 + rest];
    int o  = t & 31;
    int q0 = o >> 2;
    int s0 = ((q0 & 3) << 3) + ((q0 >> 2) << 2);
    int s1 = (((q0+1) & 3) << 3) + (((q0+1) >> 2) << 2);
    size_t ob = (size_t)rest * T_SEQ + (t & ~31);
    *(uint2*)(Vt + ob + s0) = *(const uint2*)(outv);
    *(uint2*)(Vt + ob + s1) = *(const uint2*)(outv + 4);
  }
}

// ---------------- flash attention: NO in-loop LDS, direct-from-L2 fragments --------
// 512 blocks = (head, qb). Wave w: stream st = w>>1, q-half qh = w&1 (32 q-rows).
// K/V MFMA fragments are loaded directly from the frag-interleaved global layouts
// (L2-resident), so there are NO barriers and NO LDS in the main loop -- waves run
// fully independently and pipeline their own loads. Epilogue: stream-1 waves park
// O2 in LDS; stream-0 waves combine, write Yf, accumulate LN partials.
__global__ __launch_bounds__(256) void attn_kernel(const ushort* __restrict__ Qr,
                                                   const ushort* __restrict__ Kr,
                                                   const ushort* __restrict__ Vt,
                                                   const float* __restrict__ lamp,
                                                   float* __restrict__ Yf,
                                                   float* __restrict__ part) {
  const int bx = blockIdx.x;          // 0..511
  const int h  = bx & 15;
  const int jb = bx >> 4;             // pair (jb, jb+16) sums to 32 tiles
  const int qb = (jb < 16) ? (31 - jb) : (jb - 16);
  const int kh = h >> 1;
  const int tid = threadIdx.x;
  const int lane = tid & 63;
  const int w   = tid >> 6;
  const int st  = w >> 1;             // stream 0/1
  const int qh  = w & 1;              // q-half 0/1
  const int fr  = lane & 15;
  const int fg  = (lane >> 4) * 4;
  const int g8  = (lane >> 4) * 8;

  __shared__ float ob[64 * 64];       // epilogue O2 exchange (16 KB)
  __shared__ float sb[8];

  // Q fragments for this wave's stream, two 16-q chunks (frag-interleaved global)
  bf16x8 qf[2][2];                     // [qs][ks]
  #pragma unroll
  for (int qs = 0; qs < 2; ++qs) {
    const int row = qb * 64 + qh * 32 + qs * 16 + fr;
    const ushort* qp = Qr + ((size_t)(st * NHEAD + h) * T_SEQ + row) * HDIM;
    qf[qs][0] = ldfrag128(qp + g8);
    qf[qs][1] = ldfrag128(qp + 32 + g8);
  }

  float m_[2] = {-__builtin_inff(), -__builtin_inff()};
  float l_[2] = {0.f, 0.f};
  f32x4 o_[2][4];
  #pragma unroll
  for (int qs = 0; qs < 2; ++qs)
    #pragma unroll
    for (int dn = 0; dn < 4; ++dn) o_[qs][dn] = zero4();

  // per-lane fragment base pointers (row picked by fr, 16B chunk by g8)
  const ushort* Kbase = Kr + ((size_t)(st * NKVH + kh) * T_SEQ + fr) * HDIM + g8;
  const ushort* Vbase = Vt + ((size_t)(kh * 64 + fr) * T_SEQ) + g8;

  for (int kt = 0; kt <= qb; ++kt) {
    const int kvb = kt * 64;

    // K fragments: rows kvb + n*16 + fr, halves ks (direct from L2)
    bf16x8 kf[4][2];
    #pragma unroll
    for (int n = 0; n < 4; ++n) {
      const ushort* kp = Kbase + (size_t)(kvb + n * 16) * HDIM;
      kf[n][0] = ldfrag128(kp);
      kf[n][1] = ldfrag128(kp + 32);
    }
    // V fragments: rows dn*16 + fr, t-offset kvb + ks*32 (issued early, used late)
    bf16x8 vf[4][2];
    #pragma unroll
    for (int dn = 0; dn < 4; ++dn) {
      const ushort* vp = Vbase + (size_t)(dn * 16) * T_SEQ + kvb;
      vf[dn][0] = ldfrag128(vp);
      vf[dn][1] = ldfrag128(vp + 32);
    }

    // S^T: mfma(K rows, Q cols); one K frag serves both q-chunks
    float sv[2][4][4];
    #pragma unroll
    for (int n = 0; n < 4; ++n) {
      f32x4 a0 = zero4(), a1 = zero4();
      #pragma unroll
      for (int ks = 0; ks < 2; ++ks) {
        a0 = __builtin_amdgcn_mfma_f32_16x16x32_bf16(kf[n][ks], qf[0][ks], a0, 0, 0, 0);
        a1 = __builtin_amdgcn_mfma_f32_16x16x32_bf16(kf[n][ks], qf[1][ks], a1, 0, 0, 0);
      }
      #pragma unroll
      for (int i = 0; i < 4; ++i) { sv[0][n][i] = a0[i]; sv[1][n][i] = a1[i]; }
    }
    if (kt == qb) {                  // causal mask on diagonal tile
      #pragma unroll
      for (int qs = 0; qs < 2; ++qs) {
        const int qloc = qh*32 + qs*16 + fr;
        #pragma unroll
        for (int n = 0; n < 4; ++n)
          #pragma unroll
          for (int i = 0; i < 4; ++i)
            if (n*16 + fg + i > qloc) sv[qs][n][i] = -__builtin_inff();
      }
    }

    bf16x8 pa[2][2];
    #pragma unroll
    for (int qs = 0; qs < 2; ++qs) {
      float rm = -__builtin_inff();
      #pragma unroll
      for (int n = 0; n < 4; ++n)
        #pragma unroll
        for (int i = 0; i < 4; ++i) rm = fmaxf(rm, sv[qs][n][i]);
      rm = fmaxf(rm, __shfl_xor(rm, 16));
      rm = fmaxf(rm, __shfl_xor(rm, 32));
      if (!__all(rm <= m_[qs] + 8.f)) {   // defer-max (exp2 domain, THR=8)
        float mnew = fmaxf(m_[qs], rm);
        float sc = __builtin_amdgcn_exp2f(m_[qs] - mnew);
        m_[qs] = mnew;
        l_[qs] *= sc;
        float scs[4];
        #pragma unroll
        for (int i = 0; i < 4; ++i) scs[i] = __shfl(sc, fg + i);
        #pragma unroll
        for (int dn = 0; dn < 4; ++dn)
          #pragma unroll
          for (int i = 0; i < 4; ++i) o_[qs][dn][i] *= scs[i];
      }
      float rs = 0.f;
      #pragma unroll
      for (int n = 0; n < 4; ++n)
        #pragma unroll
        for (int i = 0; i < 4; ++i) {
          float p = __builtin_amdgcn_exp2f(sv[qs][n][i] - m_[qs]);
          sv[qs][n][i] = p; rs += p;
        }
      rs += __shfl_xor(rs, 16);
      rs += __shfl_xor(rs, 32);
      l_[qs] += rs;
      #pragma unroll
      for (int ks = 0; ks < 2; ++ks)
        #pragma unroll
        for (int n2 = 0; n2 < 2; ++n2)
          #pragma unroll
          for (int i = 0; i < 4; ++i)
            pa[qs][ks][n2*4 + i] = (__bf16)sv[qs][2*ks + n2][i];
    }

    // O += P @ V; one V frag serves both q-chunks
    #pragma unroll
    for (int ks = 0; ks < 2; ++ks)
      #pragma unroll
      for (int dn = 0; dn < 4; ++dn) {
        o_[0][dn] = __builtin_amdgcn_mfma_f32_16x16x32_bf16(pa[0][ks], vf[dn][ks], o_[0][dn], 0, 0, 0);
        o_[1][dn] = __builtin_amdgcn_mfma_f32_16x16x32_bf16(pa[1][ks], vf[dn][ks], o_[1][dn], 0, 0, 0);
      }
  }

  // epilogue: normalize; exchange stream-1 O via LDS; combine + Yf + LN partials
  float iq[2][4];
  #pragma unroll
  for (int qs = 0; qs < 2; ++qs) {
    float inv = __builtin_amdgcn_rcpf(l_[qs]);
    #pragma unroll
    for (int i = 0; i < 4; ++i) iq[qs][i] = __shfl(inv, fg + i);
  }
  __syncthreads();
  if (st == 1) {
    #pragma unroll
    for (int qs = 0; qs < 2; ++qs)
      #pragma unroll
      for (int dn = 0; dn < 4; ++dn)
        #pragma unroll
        for (int i = 0; i < 4; ++i)
          ob[(qh*32 + qs*16 + fg + i)*64 + dn*16 + fr] = o_[qs][dn][i] * iq[qs][i];
  }
  __syncthreads();
  if (st == 0) {
    const float lam = *lamp;
    float s = 0.f, s2 = 0.f;
    #pragma unroll
    for (int qs = 0; qs < 2; ++qs)
      #pragma unroll
      for (int dn = 0; dn < 4; ++dn)
        #pragma unroll
        for (int i = 0; i < 4; ++i) {
          int r64 = qh*32 + qs*16 + fg + i;
          int d   = dn*16 + fr;
          float v = o_[qs][dn][i] * iq[qs][i] - lam * ob[r64*64 + d];
          Yf[(size_t)(qb*64 + r64) * DIM + h*64 + d] = v;
          s += v; s2 += v * v;
        }
    #pragma unroll
    for (int off = 1; off <= 32; off <<= 1) {
      s  += __shfl_xor(s, off);
      s2 += __shfl_xor(s2, off);
    }
    if (lane == 0) { sb[w] = s; sb[4 + w] = s2; }   // w in {0,1}
  }
  __syncthreads();
  if (tid == 0) {
    part[bx]       = sb[0] + sb[1];
    part[512 + bx] = sb[4] + sb[5];
  }
}

// ---------------- finalize per-head stats ----------------
__global__ void stats_final(const float* __restrict__ part, float* __restrict__ stat) {
  int hh = threadIdx.x;
  if (hh < 16) {
    float S = 0.f, S2 = 0.f;
    #pragma unroll
    for (int j = 0; j < 32; ++j) { S += part[j*16 + hh]; S2 += part[512 + j*16 + hh]; }
    const float N = (float)(T_SEQ * HDIM);
    float mean = S / N;
    float var  = S2 / N - mean * mean;
    stat[hh]      = mean;
    stat[16 + hh] = rsqrtf(var + 1e-5f);
  }
}

// Yb written frag-interleaved (gemm2 expects it)
__global__ void norm_cvt(const float* __restrict__ Y, const float* __restrict__ stats,
                         ushort* __restrict__ Yb) {
  int idx = (blockIdx.x * 256 + threadIdx.x) * 4;   // < T*DIM, 4-aligned
  int col = idx & (DIM - 1);
  int h = col >> 6;
  float mean = stats[h], isd = stats[16 + h] * ONE_MINUS_LI;
  float4 v = *(const float4*)(Y + idx);
  ushort4 o4;
  o4.x = f2bf((v.x - mean) * isd);
  o4.y = f2bf((v.y - mean) * isd);
  o4.z = f2bf((v.z - mean) * isd);
  o4.w = f2bf((v.w - mean) * isd);
  int q = (col & 31) >> 2;
  int idxp = (idx & ~31) + ((q & 3) << 3) + ((q >> 2) << 2);
  *(ushort4*)(Yb + idxp) = o4;
}

// ---------------- launch ----------------
extern "C" void kernel_launch(void* const* d_in, const int* in_sizes, int n_in,
                              void* d_out, int out_size, void* d_ws, size_t ws_size,
                              hipStream_t stream) {
  const float* x   = (const float*)d_in[0];
  const float* fc  = (const float*)d_in[1];
  const float* fs  = (const float*)d_in[2];
  const float* wq  = (const float*)d_in[3];
  const float* wk  = (const float*)d_in[4];
  const float* wv  = (const float*)d_in[5];
  const float* wo  = (const float*)d_in[6];
  const float* lq1 = (const float*)d_in[7];
  const float* lk1 = (const float*)d_in[8];
  const float* lq2 = (const float*)d_in[9];
  const float* lk2 = (const float*)d_in[10];
  float* out = (float*)d_out;

  char* ws = (char*)d_ws;
  const size_t OFF_WOB  = 0;                 // 2 MB, live till end
  const size_t OFF_XB   = 2097152;           // 4 MB, dead after gemm1
  const size_t OFF_WB   = 6291456;           // 7 MB, dead after gemm1
  const size_t OFF_QKV  = 13631488;          // 14.68 MB, dead after reorg
  const size_t OFF_QR   = 28311552;          // 8 MB
  const size_t OFF_KR   = 36700160;          // 4 MB
  const size_t OFF_VT   = 40894464;          // 2 MB
  const size_t OFF_Y    = 18874368;          // 8 MB over dead QKV tail
  const size_t OFF_YB   = 42991616;          // 4 MB
  const size_t OFF_ST   = 47185920;          // stats + lam + partials

  ushort* xb   = (ushort*)(ws + OFF_XB);
  ushort* Wb   = (ushort*)(ws + OFF_WB);
  ushort* Wob  = (ushort*)(ws + OFF_WOB);
  ushort* QKVb = (ushort*)(ws + OFF_QKV);
  ushort* Qr   = (ushort*)(ws + OFF_QR);
  ushort* Kr   = (ushort*)(ws + OFF_KR);
  ushort* Vt   = (ushort*)(ws + OFF_VT);
  float*  Yf   = (float*)(ws + OFF_Y);
  ushort* Yb   = (ushort*)(ws + OFF_YB);
  float*  stat = (float*)(ws + OFF_ST);
  float*  lamp = stat + 32;
  float*  part = stat + 64;                  // 1024 floats

  cvt_all<<<6656, 256, 0, stream>>>(x, wq, wk, wv, wo, xb, Wb, Wob);
  lam_kernel<<<1, 64, 0, stream>>>(lq1, lk1, lq2, lk2, lamp);

  gemm_bt<1><<<dim3(QKVN/128, T_SEQ/128), 256, 0, stream>>>(xb, Wb, QKVb, T_SEQ, QKVN, DIM);

  reorg<<<3584, 256, 0, stream>>>(QKVb, Qr, Kr, Vt, fc, fs);

  attn_kernel<<<512, 256, 0, stream>>>(Qr, Kr, Vt, lamp, Yf, part);

  stats_final<<<1, 64, 0, stream>>>(part, stat);
  norm_cvt<<<2048, 256, 0, stream>>>(Yf, stat, Yb);

  gemm_bt<0><<<dim3(DIM/128, T_SEQ/128), 256, 0, stream>>>(Yb, Wob, out, T_SEQ, DIM, DIM);
}